// Round 9
// baseline (567.344 us; speedup 1.0000x reference)
//
#include <hip/hip_runtime.h>
#include <hip/hip_bf16.h>

#define TT 2048
#define CCH 1024
#define HH 16
#define DD 64
#define BB 4
#define MM (BB*TT)

typedef __attribute__((ext_vector_type(4))) float f32x4;
typedef __attribute__((ext_vector_type(8))) short short8;
typedef __attribute__((ext_vector_type(8))) unsigned short u16x8;
typedef __attribute__((ext_vector_type(4))) unsigned short u16x4;

__device__ __forceinline__ unsigned short f2b(float f) {
    unsigned int u = __float_as_uint(f);
    u += 0x7fffu + ((u >> 16) & 1u);
    return (unsigned short)(u >> 16);
}
__device__ __forceinline__ float b2f(unsigned short u) {
    return __uint_as_float(((unsigned int)u) << 16);
}
__device__ __forceinline__ int finite_f(float v) {
    return ((__float_as_uint(v) >> 23) & 0xFFu) != 0xFFu;
}
__device__ __forceinline__ float exp2_hw(float x) {
    return __builtin_amdgcn_exp2f(x);
}

// ---------------- input-dtype detector ----------------
__global__ __launch_bounds__(64) void detect_k(const unsigned int* __restrict__ x,
                                               int* __restrict__ flag) {
    int tid = threadIdx.x;
    int cnt = 0;
#pragma unroll
    for (int i = 0; i < 16; ++i) {
        unsigned int w = x[tid * 16 + i];
        unsigned int lo = w & 0xFFFFu;
        unsigned int e = (lo >> 7) & 0xFFu;
        if ((e >= 0x62u && e <= 0x90u) || lo == 0u) ++cnt;
    }
#pragma unroll
    for (int o = 32; o; o >>= 1) cnt += __shfl_down(cnt, o);
    if (tid == 0) *flag = (cnt >= 640) ? 1 : 0;
}

// ------------- W transpose(+cast): [R][Cc] -> bf16 [Cc][R] -------------
__global__ __launch_bounds__(256) void wtrans_k(const void* __restrict__ in,
                                                unsigned short* __restrict__ out,
                                                int R, int Cc,
                                                const int* __restrict__ flag) {
    __shared__ float tile[32][33];
    const int tid = threadIdx.x;
    const int c0 = blockIdx.x * 32, r0 = blockIdx.y * 32;
    const int isb = *flag;
#pragma unroll
    for (int i = 0; i < 4; ++i) {
        int e = i * 256 + tid;
        int row = e >> 5, col = e & 31;
        size_t idx = (size_t)(r0 + row) * Cc + (c0 + col);
        tile[row][col] = isb ? b2f(((const unsigned short*)in)[idx])
                             : ((const float*)in)[idx];
    }
    __syncthreads();
#pragma unroll
    for (int i = 0; i < 4; ++i) {
        int e = i * 256 + tid;
        int crow = e >> 5, rcol = e & 31;
        out[(size_t)(c0 + crow) * R + (r0 + rcol)] = f2b(tile[rcol][crow]);
    }
}

// ------------- V transpose: bf16 [bh][2048][64] -> [bh][64][2048] -------------
__global__ __launch_bounds__(256) void vtrans_k(const unsigned short* __restrict__ V,
                                                unsigned short* __restrict__ VT) {
    __shared__ unsigned short tile[64][68];
    const int tid = threadIdx.x;
    const int t0 = blockIdx.x * 64;
    const int bh = blockIdx.y;
    const unsigned short* in = V + ((size_t)bh * TT + t0) * DD;
#pragma unroll
    for (int i = 0; i < 4; ++i) {
        int cid = i * 256 + tid;
        int row = cid >> 4;
        int ch  = cid & 15;
        u16x4 v = *(const u16x4*)(in + row * DD + ch * 4);
        *(u16x4*)&tile[row][ch * 4] = v;
    }
    __syncthreads();
    unsigned short* out = VT + (size_t)bh * DD * TT + t0;
#pragma unroll
    for (int i = 0; i < 4; ++i) {
        int cid = i * 256 + tid;
        int drow = cid >> 4;
        int tch  = cid & 15;
        u16x4 v;
        v[0] = tile[tch * 4 + 0][drow];
        v[1] = tile[tch * 4 + 1][drow];
        v[2] = tile[tch * 4 + 2][drow];
        v[3] = tile[tch * 4 + 3][drow];
        *(u16x4*)(out + (size_t)drow * TT + tch * 4) = v;
    }
}

// -------- QKV GEMM: x[M][K] (fp32|bf16) @ WqkvT[N][K] bf16 + bias --------
__global__ __launch_bounds__(256) void gemm_qkv(const void* __restrict__ x,
                                                const unsigned short* __restrict__ Bt,
                                                const void* __restrict__ bias,
                                                unsigned short* __restrict__ outQ,
                                                unsigned short* __restrict__ outK,
                                                unsigned short* __restrict__ outV,
                                                const int* __restrict__ flag) {
    __shared__ unsigned short As[128 * 32];
    __shared__ unsigned short Bs[128 * 32];
    const int Ksz = CCH;
    const int tid = threadIdx.x;
    const int lane = tid & 63;
    const int wid = tid >> 6;
    const int bm = blockIdx.y * 128;
    const int bn = blockIdx.x * 128;
    const int wm = (wid >> 1) * 64;
    const int wn = (wid & 1) * 64;
    const int sr = tid >> 2;
    const int sc = (tid & 3) * 8;
    const int l15 = lane & 15, l4 = lane >> 4;
    const int isb = *flag;

    f32x4 acc[4][4];
#pragma unroll
    for (int i = 0; i < 4; ++i)
#pragma unroll
        for (int j = 0; j < 4; ++j)
            acc[i][j] = (f32x4){0.f, 0.f, 0.f, 0.f};

    const size_t aoff0 = (size_t)(bm + sr) * Ksz + sc;
    const size_t aoff1 = aoff0 + (size_t)64 * Ksz;
    const unsigned short* pb0 = Bt + (size_t)(bn + sr) * Ksz + sc;
    const unsigned short* pb1 = pb0 + (size_t)64 * Ksz;

    auto lda = [&](size_t off) -> u16x8 {
        if (isb) return *(const u16x8*)((const unsigned short*)x + off);
        const float4* p = (const float4*)((const float*)x + off);
        float4 v0 = p[0], v1 = p[1];
        u16x8 o;
        o[0] = f2b(v0.x); o[1] = f2b(v0.y); o[2] = f2b(v0.z); o[3] = f2b(v0.w);
        o[4] = f2b(v1.x); o[5] = f2b(v1.y); o[6] = f2b(v1.z); o[7] = f2b(v1.w);
        return o;
    };

    u16x8 a0 = lda(aoff0);
    u16x8 a1 = lda(aoff1);
    u16x8 b0 = *(const u16x8*)(pb0);
    u16x8 b1 = *(const u16x8*)(pb1);

    for (int kt = 0; kt < Ksz; kt += 32) {
        __syncthreads();
        *(u16x8*)&As[sr * 32 + sc] = a0;
        *(u16x8*)&As[(sr + 64) * 32 + sc] = a1;
        *(u16x8*)&Bs[sr * 32 + sc] = b0;
        *(u16x8*)&Bs[(sr + 64) * 32 + sc] = b1;
        if (kt + 32 < Ksz) {
            a0 = lda(aoff0 + kt + 32);
            a1 = lda(aoff1 + kt + 32);
            b0 = *(const u16x8*)(pb0 + kt + 32);
            b1 = *(const u16x8*)(pb1 + kt + 32);
        }
        __syncthreads();
        short8 af[4], bfr[4];
#pragma unroll
        for (int mi = 0; mi < 4; ++mi)
            af[mi] = *(const short8*)&As[(wm + mi * 16 + l15) * 32 + l4 * 8];
#pragma unroll
        for (int ni = 0; ni < 4; ++ni)
            bfr[ni] = *(const short8*)&Bs[(wn + ni * 16 + l15) * 32 + l4 * 8];
#pragma unroll
        for (int mi = 0; mi < 4; ++mi)
#pragma unroll
            for (int ni = 0; ni < 4; ++ni)
                acc[mi][ni] = __builtin_amdgcn_mfma_f32_16x16x32_bf16(
                    af[mi], bfr[ni], acc[mi][ni], 0, 0, 0);
    }

#pragma unroll
    for (int mi = 0; mi < 4; ++mi) {
#pragma unroll
        for (int ni = 0; ni < 4; ++ni) {
            const int col = bn + wn + ni * 16 + l15;
            const float bv = isb ? b2f(((const unsigned short*)bias)[col])
                                 : ((const float*)bias)[col];
#pragma unroll
            for (int r = 0; r < 4; ++r) {
                const int row = bm + wm + mi * 16 + l4 * 4 + r;
                float v = acc[mi][ni][r] + bv;
                const int which = col >> 10;
                const int h = (col >> 6) & 15;
                const int d = col & 63;
                const int b = row >> 11, t = row & 2047;
                const size_t idx = (((size_t)b * HH + h) * TT + t) * DD + d;
                if (which == 0)      outQ[idx] = f2b(v * 0.18033688f);  // /sqrt(64)*log2e
                else if (which == 1) outK[idx] = f2b(v);
                else                 outV[idx] = f2b(v);
            }
        }
    }
}

// ---------------- flash attention v4: 4-way split-KV, residency-tuned ----------------
// Block = 4 waves = ONE q-tile pair {qt,127-qt}; wave h (=wid) handles KV
// 64-blocks with index ≡ h (mod 4). Partials merged in LDS; h=0 writes.
// T13 defer-max; tree reductions; uniform causal-mask skip; setprio on MFMA.
__global__ __launch_bounds__(256, 6) void attn_k(unsigned short* __restrict__ Q,
                                                 const unsigned short* __restrict__ K,
                                                 const unsigned short* __restrict__ VT) {
    __shared__ unsigned short Plds[4][16][64];   // swizzled P round-trip (per wave)
    __shared__ unsigned short Olds[64][18];      // epilogue transpose (h=0 only)
    __shared__ float Mrg[3][64][18];             // partials from h=1..3: {m,l,ot[16]}
    const int tid = threadIdx.x, lane = tid & 63, h = tid >> 6;
    const int bid = blockIdx.x;
    const int swb = (bid & 7) * 512 + (bid >> 3);   // XCD swizzle (4096%8==0)
    const int bh = swb >> 6;                    // 0..63
    const int pair = swb & 63;                  // 0..63
    const int l15 = lane & 15, l4 = lane >> 4;
    unsigned short* Qp = Q + (size_t)bh * TT * DD;
    const unsigned short* Kp = K + (size_t)bh * TT * DD;
    const unsigned short* Vp = VT + (size_t)bh * DD * TT;
    const int swz = (l15 & 7) << 4;
    unsigned char* prow = (unsigned char*)&Plds[h][l15][0];

#pragma unroll 1
    for (int hv = 0; hv < 2; ++hv) {
        const int qt = hv ? (127 - pair) : pair;
        const int qw = qt << 4;
        const int qi = qw + l15;
        const int kend = qw + 16;

        short8 qf0 = *(const short8*)(Qp + (size_t)(qw + l15) * DD + l4 * 8);
        short8 qf1 = *(const short8*)(Qp + (size_t)(qw + l15) * DD + 32 + l4 * 8);

        f32x4 ot[4];
#pragma unroll
        for (int c = 0; c < 4; ++c) ot[c] = (f32x4){0.f, 0.f, 0.f, 0.f};
        float m = -1e30f, lsum = 0.f;

#pragma unroll 1
        for (int kb = h * 64; kb < kend; kb += 256) {
            // QK^T in two K-halves (lower VGPR peak)
            f32x4 st[4];
            __builtin_amdgcn_s_setprio(1);
#pragma unroll
            for (int half = 0; half < 2; ++half) {
#pragma unroll
                for (int t = 0; t < 2; ++t) {
                    const unsigned short* kr =
                        Kp + (size_t)(kb + half * 32 + t * 16 + l15) * DD + l4 * 8;
                    short8 kfa = *(const short8*)(kr);
                    short8 kfb = *(const short8*)(kr + 32);
                    f32x4 z = (f32x4){0.f, 0.f, 0.f, 0.f};
                    z = __builtin_amdgcn_mfma_f32_16x16x32_bf16(kfa, qf0, z, 0, 0, 0);
                    z = __builtin_amdgcn_mfma_f32_16x16x32_bf16(kfb, qf1, z, 0, 0, 0);
                    st[half * 2 + t] = z;
                }
            }
            __builtin_amdgcn_s_setprio(0);
            // V fragments: issue now, consumed after softmax
            short8 vf[4][2];
#pragma unroll
            for (int c = 0; c < 4; ++c)
#pragma unroll
                for (int ch = 0; ch < 2; ++ch)
                    vf[c][ch] = *(const short8*)(Vp + (size_t)(c * 16 + l15) * TT
                                                 + kb + ch * 32 + l4 * 8);
            // causal mask only on the diagonal iteration (uniform test)
            if (!(kb + 63 <= qw)) {
#pragma unroll
                for (int t = 0; t < 4; ++t)
#pragma unroll
                    for (int r = 0; r < 4; ++r) {
                        const int kpos = kb + t * 16 + l4 * 4 + r;
                        st[t][r] = (kpos > qi) ? -30000.f : st[t][r];
                    }
            }
            // tree max over 16 values (depth 4), then 4-lane-group reduce
            float mx01 = fmaxf(fmaxf(st[0][0], st[0][1]), fmaxf(st[0][2], st[0][3]));
            float mx23 = fmaxf(fmaxf(st[1][0], st[1][1]), fmaxf(st[1][2], st[1][3]));
            float mx45 = fmaxf(fmaxf(st[2][0], st[2][1]), fmaxf(st[2][2], st[2][3]));
            float mx67 = fmaxf(fmaxf(st[3][0], st[3][1]), fmaxf(st[3][2], st[3][3]));
            float tmax = fmaxf(fmaxf(mx01, mx23), fmaxf(mx45, mx67));
            tmax = fmaxf(tmax, __shfl_xor(tmax, 16));
            tmax = fmaxf(tmax, __shfl_xor(tmax, 32));
            // T13 defer-max: skip rescale unless max grew past threshold
            if (!__all(tmax <= m + 8.f)) {
                const float mnew = fmaxf(m, tmax);
                const float corr = exp2_hw(m - mnew);
                lsum *= corr;
#pragma unroll
                for (int c = 0; c < 4; ++c) ot[c] *= corr;
                m = mnew;
            }
            // P = exp2(S - m), tree-sum, pack bf16
            float pv[16];
            u16x4 pw[4];
#pragma unroll
            for (int t = 0; t < 4; ++t)
#pragma unroll
                for (int r = 0; r < 4; ++r) {
                    float p = exp2_hw(st[t][r] - m);
                    pv[t * 4 + r] = p;
                    pw[t][r] = f2b(p);
                }
            float s0 = (pv[0] + pv[1]) + (pv[2] + pv[3]);
            float s1 = (pv[4] + pv[5]) + (pv[6] + pv[7]);
            float s2 = (pv[8] + pv[9]) + (pv[10] + pv[11]);
            float s3 = (pv[12] + pv[13]) + (pv[14] + pv[15]);
            lsum += (s0 + s1) + (s2 + s3);
            // P -> LDS (swizzled), read back as PV B-fragments
#pragma unroll
            for (int t = 0; t < 4; ++t)
                *(u16x4*)(prow + ((t * 32 + l4 * 8) ^ swz)) = pw[t];
            asm volatile("" ::: "memory");
            short8 pb0 = *(const short8*)(prow + ((l4 * 16) ^ swz));
            short8 pb1 = *(const short8*)(prow + ((64 + l4 * 16) ^ swz));
            asm volatile("" ::: "memory");
            __builtin_amdgcn_s_setprio(1);
#pragma unroll
            for (int c = 0; c < 4; ++c) {
                ot[c] = __builtin_amdgcn_mfma_f32_16x16x32_bf16(vf[c][0], pb0, ot[c], 0, 0, 0);
                ot[c] = __builtin_amdgcn_mfma_f32_16x16x32_bf16(vf[c][1], pb1, ot[c], 0, 0, 0);
            }
            __builtin_amdgcn_s_setprio(0);
        }

        // per-row denominator partial
        float ls = lsum + __shfl_xor(lsum, 16);
        ls += __shfl_xor(ls, 32);

        if (h > 0) {   // publish partial
            float* mb = &Mrg[h - 1][lane][0];
            mb[0] = m;
            mb[1] = ls;
#pragma unroll
            for (int c = 0; c < 4; ++c)
#pragma unroll
                for (int r = 0; r < 4; ++r) mb[2 + c * 4 + r] = ot[c][r];
        }
        __syncthreads();
        if (h == 0) {   // merge 4 partials, normalize, write over Q rows
            float mj[3], lj[3];
#pragma unroll
            for (int j = 0; j < 3; ++j) {
                mj[j] = Mrg[j][lane][0];
                lj[j] = Mrg[j][lane][1];
            }
            float mstar = fmaxf(fmaxf(m, mj[0]), fmaxf(mj[1], mj[2]));
            const float cs = exp2_hw(m - mstar);
            float cj[3];
            float den = ls * cs;
#pragma unroll
            for (int j = 0; j < 3; ++j) {
                cj[j] = exp2_hw(mj[j] - mstar);
                den += lj[j] * cj[j];
            }
            const float inv = 1.f / den;
#pragma unroll
            for (int c = 0; c < 4; ++c)
#pragma unroll
                for (int r = 0; r < 4; ++r) {
                    float v = ot[c][r] * cs;
#pragma unroll
                    for (int j = 0; j < 3; ++j)
                        v += Mrg[j][lane][2 + c * 4 + r] * cj[j];
                    v *= inv;
                    if (!finite_f(v)) v = 200.0f;   // canary
                    Olds[c * 16 + l4 * 4 + r][l15] = f2b(v);
                }
            asm volatile("" ::: "memory");
            const int q2 = lane >> 2, c8 = lane & 3;
#pragma unroll
            for (int s = 0; s < 2; ++s) {
                u16x8 o;
#pragma unroll
                for (int j = 0; j < 8; ++j) o[j] = Olds[s * 32 + c8 * 8 + j][q2];
                *(u16x8*)(Qp + (size_t)(qw + q2) * DD + s * 32 + c8 * 8) = o;
            }
        }
        __syncthreads();   // protect Mrg/Olds before next hv
    }
}

// -------- proj GEMM: Y([b][h][t][d] in Q region) @ WprojT + bias -> out fp32 --------
__global__ __launch_bounds__(256) void gemm_proj(const unsigned short* __restrict__ A,
                                                 const unsigned short* __restrict__ Bt,
                                                 const void* __restrict__ bias,
                                                 float* __restrict__ outO,
                                                 const int* __restrict__ flag) {
    __shared__ unsigned short As[128 * 32];
    __shared__ unsigned short Bs[128 * 32];
    const int Ksz = CCH;
    const int tid = threadIdx.x;
    const int lane = tid & 63;
    const int wid = tid >> 6;
    const int bm = blockIdx.y * 128;
    const int bn = blockIdx.x * 128;
    const int wm = (wid >> 1) * 64;
    const int wn = (wid & 1) * 64;
    const int sr = tid >> 2;
    const int sc = (tid & 3) * 8;
    const int l15 = lane & 15, l4 = lane >> 4;
    const int isb = *flag;

    f32x4 acc[4][4];
#pragma unroll
    for (int i = 0; i < 4; ++i)
#pragma unroll
        for (int j = 0; j < 4; ++j)
            acc[i][j] = (f32x4){0.f, 0.f, 0.f, 0.f};

    const int m0 = bm + sr;
    const unsigned short* Ar0 = A + (size_t)(m0 >> 11) * (HH * TT * DD)
                                  + (size_t)(m0 & 2047) * DD;
    const unsigned short* Ar1 = Ar0 + (size_t)64 * DD;
    const unsigned short* pb0 = Bt + (size_t)(bn + sr) * Ksz + sc;
    const unsigned short* pb1 = pb0 + (size_t)64 * Ksz;

    auto aoff = [&](int kt) -> size_t {
        return (size_t)(kt >> 6) * (TT * DD) + (kt & 32) + sc;
    };

    u16x8 a0 = *(const u16x8*)(Ar0 + aoff(0));
    u16x8 a1 = *(const u16x8*)(Ar1 + aoff(0));
    u16x8 b0 = *(const u16x8*)(pb0);
    u16x8 b1 = *(const u16x8*)(pb1);

    for (int kt = 0; kt < Ksz; kt += 32) {
        __syncthreads();
        *(u16x8*)&As[sr * 32 + sc] = a0;
        *(u16x8*)&As[(sr + 64) * 32 + sc] = a1;
        *(u16x8*)&Bs[sr * 32 + sc] = b0;
        *(u16x8*)&Bs[(sr + 64) * 32 + sc] = b1;
        if (kt + 32 < Ksz) {
            a0 = *(const u16x8*)(Ar0 + aoff(kt + 32));
            a1 = *(const u16x8*)(Ar1 + aoff(kt + 32));
            b0 = *(const u16x8*)(pb0 + kt + 32);
            b1 = *(const u16x8*)(pb1 + kt + 32);
        }
        __syncthreads();
        short8 af[4], bfr[4];
#pragma unroll
        for (int mi = 0; mi < 4; ++mi)
            af[mi] = *(const short8*)&As[(wm + mi * 16 + l15) * 32 + l4 * 8];
#pragma unroll
        for (int ni = 0; ni < 4; ++ni)
            bfr[ni] = *(const short8*)&Bs[(wn + ni * 16 + l15) * 32 + l4 * 8];
#pragma unroll
        for (int mi = 0; mi < 4; ++mi)
#pragma unroll
            for (int ni = 0; ni < 4; ++ni)
                acc[mi][ni] = __builtin_amdgcn_mfma_f32_16x16x32_bf16(
                    af[mi], bfr[ni], acc[mi][ni], 0, 0, 0);
    }

#pragma unroll
    for (int mi = 0; mi < 4; ++mi) {
#pragma unroll
        for (int ni = 0; ni < 4; ++ni) {
            const int col = bn + wn + ni * 16 + l15;
            const float bv = isb ? b2f(((const unsigned short*)bias)[col])
                                 : ((const float*)bias)[col];
#pragma unroll
            for (int r = 0; r < 4; ++r) {
                const int row = bm + wm + mi * 16 + l4 * 4 + r;
                float v = acc[mi][ni][r] + bv;
                if (!finite_f(v)) v = 300.0f;   // canary
                outO[(size_t)row * CCH + col] = v;
            }
        }
    }
}

extern "C" void kernel_launch(void* const* d_in, const int* in_sizes, int n_in,
                              void* d_out, int out_size, void* d_ws, size_t ws_size,
                              hipStream_t stream) {
    const void* x     = d_in[0];
    const void* Wqkv  = d_in[1];
    const void* bqkv  = d_in[2];
    const void* Wproj = d_in[3];
    const void* bproj = d_in[4];
    float* out = (float*)d_out;

    char* w = (char*)d_ws;
    int* flag = (int*)w;                          w += 256;
    unsigned short* wqkvT  = (unsigned short*)w;  w += (size_t)3 * CCH * CCH * 2;
    unsigned short* wprojT = (unsigned short*)w;  w += (size_t)CCH * CCH * 2;
    unsigned short* Qb     = (unsigned short*)w;  w += (size_t)MM * CCH * 2;
    unsigned short* Kb     = (unsigned short*)w;  w += (size_t)MM * CCH * 2;
    unsigned short* VTb    = (unsigned short*)w;  w += (size_t)MM * CCH * 2;
    unsigned short* Vstage = (unsigned short*)d_out;  // d_out as V scratch

    detect_k<<<1, 64, 0, stream>>>((const unsigned int*)x, flag);
    wtrans_k<<<dim3(96, 32), 256, 0, stream>>>(Wqkv, wqkvT, CCH, 3 * CCH, flag);
    wtrans_k<<<dim3(32, 32), 256, 0, stream>>>(Wproj, wprojT, CCH, CCH, flag);
    gemm_qkv<<<dim3(24, 64), 256, 0, stream>>>(x, wqkvT, bqkv, Qb, Kb, Vstage, flag);
    vtrans_k<<<dim3(32, 64), 256, 0, stream>>>(Vstage, VTb);
    attn_k<<<4096, 256, 0, stream>>>(Qb, Kb, VTb);          // writes Y over Q rows
    gemm_proj<<<dim3(8, 64), 256, 0, stream>>>(Qb, wprojT, bproj, out, flag);
}

// Round 10
// 394.208 us; speedup vs baseline: 1.4392x; 1.4392x over previous
//
#include <hip/hip_runtime.h>
#include <hip/hip_bf16.h>

#define TT 2048
#define CCH 1024
#define HH 16
#define DD 64
#define BB 4
#define MM (BB*TT)

typedef __attribute__((ext_vector_type(4))) float f32x4;
typedef __attribute__((ext_vector_type(8))) short short8;
typedef __attribute__((ext_vector_type(8))) unsigned short u16x8;
typedef __attribute__((ext_vector_type(4))) unsigned short u16x4;

__device__ __forceinline__ unsigned short f2b(float f) {
    unsigned int u = __float_as_uint(f);
    u += 0x7fffu + ((u >> 16) & 1u);
    return (unsigned short)(u >> 16);
}
__device__ __forceinline__ float b2f(unsigned short u) {
    return __uint_as_float(((unsigned int)u) << 16);
}
__device__ __forceinline__ int finite_f(float v) {
    return ((__float_as_uint(v) >> 23) & 0xFFu) != 0xFFu;
}
__device__ __forceinline__ float exp2_hw(float x) {
    return __builtin_amdgcn_exp2f(x);
}

// ---------------- input-dtype detector ----------------
__global__ __launch_bounds__(64) void detect_k(const unsigned int* __restrict__ x,
                                               int* __restrict__ flag) {
    int tid = threadIdx.x;
    int cnt = 0;
#pragma unroll
    for (int i = 0; i < 16; ++i) {
        unsigned int w = x[tid * 16 + i];
        unsigned int lo = w & 0xFFFFu;
        unsigned int e = (lo >> 7) & 0xFFu;
        if ((e >= 0x62u && e <= 0x90u) || lo == 0u) ++cnt;
    }
#pragma unroll
    for (int o = 32; o; o >>= 1) cnt += __shfl_down(cnt, o);
    if (tid == 0) *flag = (cnt >= 640) ? 1 : 0;
}

// ------------- W transpose(+cast): [R][Cc] -> bf16 [Cc][R] -------------
__global__ __launch_bounds__(256) void wtrans_k(const void* __restrict__ in,
                                                unsigned short* __restrict__ out,
                                                int R, int Cc,
                                                const int* __restrict__ flag) {
    __shared__ float tile[32][33];
    const int tid = threadIdx.x;
    const int c0 = blockIdx.x * 32, r0 = blockIdx.y * 32;
    const int isb = *flag;
#pragma unroll
    for (int i = 0; i < 4; ++i) {
        int e = i * 256 + tid;
        int row = e >> 5, col = e & 31;
        size_t idx = (size_t)(r0 + row) * Cc + (c0 + col);
        tile[row][col] = isb ? b2f(((const unsigned short*)in)[idx])
                             : ((const float*)in)[idx];
    }
    __syncthreads();
#pragma unroll
    for (int i = 0; i < 4; ++i) {
        int e = i * 256 + tid;
        int crow = e >> 5, rcol = e & 31;
        out[(size_t)(c0 + crow) * R + (r0 + rcol)] = f2b(tile[rcol][crow]);
    }
}

// ------------- V transpose: bf16 [bh][2048][64] -> [bh][64][2048] -------------
__global__ __launch_bounds__(256) void vtrans_k(const unsigned short* __restrict__ V,
                                                unsigned short* __restrict__ VT) {
    __shared__ unsigned short tile[64][68];
    const int tid = threadIdx.x;
    const int t0 = blockIdx.x * 64;
    const int bh = blockIdx.y;
    const unsigned short* in = V + ((size_t)bh * TT + t0) * DD;
#pragma unroll
    for (int i = 0; i < 4; ++i) {
        int cid = i * 256 + tid;
        int row = cid >> 4;
        int ch  = cid & 15;
        u16x4 v = *(const u16x4*)(in + row * DD + ch * 4);
        *(u16x4*)&tile[row][ch * 4] = v;
    }
    __syncthreads();
    unsigned short* out = VT + (size_t)bh * DD * TT + t0;
#pragma unroll
    for (int i = 0; i < 4; ++i) {
        int cid = i * 256 + tid;
        int drow = cid >> 4;
        int tch  = cid & 15;
        u16x4 v;
        v[0] = tile[tch * 4 + 0][drow];
        v[1] = tile[tch * 4 + 1][drow];
        v[2] = tile[tch * 4 + 2][drow];
        v[3] = tile[tch * 4 + 3][drow];
        *(u16x4*)(out + (size_t)drow * TT + tch * 4) = v;
    }
}

// -------- QKV GEMM: x[M][K] (fp32|bf16) @ WqkvT[N][K] bf16 + bias --------
__global__ __launch_bounds__(256) void gemm_qkv(const void* __restrict__ x,
                                                const unsigned short* __restrict__ Bt,
                                                const void* __restrict__ bias,
                                                unsigned short* __restrict__ outQ,
                                                unsigned short* __restrict__ outK,
                                                unsigned short* __restrict__ outV,
                                                const int* __restrict__ flag) {
    __shared__ unsigned short As[128 * 32];
    __shared__ unsigned short Bs[128 * 32];
    const int Ksz = CCH;
    const int tid = threadIdx.x;
    const int lane = tid & 63;
    const int wid = tid >> 6;
    const int bm = blockIdx.y * 128;
    const int bn = blockIdx.x * 128;
    const int wm = (wid >> 1) * 64;
    const int wn = (wid & 1) * 64;
    const int sr = tid >> 2;
    const int sc = (tid & 3) * 8;
    const int l15 = lane & 15, l4 = lane >> 4;
    const int isb = *flag;

    f32x4 acc[4][4];
#pragma unroll
    for (int i = 0; i < 4; ++i)
#pragma unroll
        for (int j = 0; j < 4; ++j)
            acc[i][j] = (f32x4){0.f, 0.f, 0.f, 0.f};

    const size_t aoff0 = (size_t)(bm + sr) * Ksz + sc;
    const size_t aoff1 = aoff0 + (size_t)64 * Ksz;
    const unsigned short* pb0 = Bt + (size_t)(bn + sr) * Ksz + sc;
    const unsigned short* pb1 = pb0 + (size_t)64 * Ksz;

    auto lda = [&](size_t off) -> u16x8 {
        if (isb) return *(const u16x8*)((const unsigned short*)x + off);
        const float4* p = (const float4*)((const float*)x + off);
        float4 v0 = p[0], v1 = p[1];
        u16x8 o;
        o[0] = f2b(v0.x); o[1] = f2b(v0.y); o[2] = f2b(v0.z); o[3] = f2b(v0.w);
        o[4] = f2b(v1.x); o[5] = f2b(v1.y); o[6] = f2b(v1.z); o[7] = f2b(v1.w);
        return o;
    };

    u16x8 a0 = lda(aoff0);
    u16x8 a1 = lda(aoff1);
    u16x8 b0 = *(const u16x8*)(pb0);
    u16x8 b1 = *(const u16x8*)(pb1);

    for (int kt = 0; kt < Ksz; kt += 32) {
        __syncthreads();
        *(u16x8*)&As[sr * 32 + sc] = a0;
        *(u16x8*)&As[(sr + 64) * 32 + sc] = a1;
        *(u16x8*)&Bs[sr * 32 + sc] = b0;
        *(u16x8*)&Bs[(sr + 64) * 32 + sc] = b1;
        if (kt + 32 < Ksz) {
            a0 = lda(aoff0 + kt + 32);
            a1 = lda(aoff1 + kt + 32);
            b0 = *(const u16x8*)(pb0 + kt + 32);
            b1 = *(const u16x8*)(pb1 + kt + 32);
        }
        __syncthreads();
        short8 af[4], bfr[4];
#pragma unroll
        for (int mi = 0; mi < 4; ++mi)
            af[mi] = *(const short8*)&As[(wm + mi * 16 + l15) * 32 + l4 * 8];
#pragma unroll
        for (int ni = 0; ni < 4; ++ni)
            bfr[ni] = *(const short8*)&Bs[(wn + ni * 16 + l15) * 32 + l4 * 8];
#pragma unroll
        for (int mi = 0; mi < 4; ++mi)
#pragma unroll
            for (int ni = 0; ni < 4; ++ni)
                acc[mi][ni] = __builtin_amdgcn_mfma_f32_16x16x32_bf16(
                    af[mi], bfr[ni], acc[mi][ni], 0, 0, 0);
    }

#pragma unroll
    for (int mi = 0; mi < 4; ++mi) {
#pragma unroll
        for (int ni = 0; ni < 4; ++ni) {
            const int col = bn + wn + ni * 16 + l15;
            const float bv = isb ? b2f(((const unsigned short*)bias)[col])
                                 : ((const float*)bias)[col];
#pragma unroll
            for (int r = 0; r < 4; ++r) {
                const int row = bm + wm + mi * 16 + l4 * 4 + r;
                float v = acc[mi][ni][r] + bv;
                const int which = col >> 10;
                const int h = (col >> 6) & 15;
                const int d = col & 63;
                const int b = row >> 11, t = row & 2047;
                const size_t idx = (((size_t)b * HH + h) * TT + t) * DD + d;
                if (which == 0)      outQ[idx] = f2b(v * 0.18033688f);  // /sqrt(64)*log2e
                else if (which == 1) outK[idx] = f2b(v);
                else                 outV[idx] = f2b(v);
            }
        }
    }
}

// ---------------- flash attention v4b: 4-way split-KV, spill-free ----------------
// Identical structure to v4 (round 9); ONLY change: __launch_bounds__(256,4)
// instead of (256,6). Round 9's cap forced VGPR=40 -> massive scratch spills
// (WRITE_SIZE 852 MB). Budget 128 VGPRs fits the kernel's natural ~100.
__global__ __launch_bounds__(256, 4) void attn_k(unsigned short* __restrict__ Q,
                                                 const unsigned short* __restrict__ K,
                                                 const unsigned short* __restrict__ VT) {
    __shared__ unsigned short Plds[4][16][64];   // swizzled P round-trip (per wave)
    __shared__ unsigned short Olds[64][18];      // epilogue transpose (h=0 only)
    __shared__ float Mrg[3][64][18];             // partials from h=1..3: {m,l,ot[16]}
    const int tid = threadIdx.x, lane = tid & 63, h = tid >> 6;
    const int bid = blockIdx.x;
    const int swb = (bid & 7) * 512 + (bid >> 3);   // XCD swizzle (4096%8==0)
    const int bh = swb >> 6;                    // 0..63
    const int pair = swb & 63;                  // 0..63
    const int l15 = lane & 15, l4 = lane >> 4;
    unsigned short* Qp = Q + (size_t)bh * TT * DD;
    const unsigned short* Kp = K + (size_t)bh * TT * DD;
    const unsigned short* Vp = VT + (size_t)bh * DD * TT;
    const int swz = (l15 & 7) << 4;
    unsigned char* prow = (unsigned char*)&Plds[h][l15][0];

#pragma unroll 1
    for (int hv = 0; hv < 2; ++hv) {
        const int qt = hv ? (127 - pair) : pair;
        const int qw = qt << 4;
        const int qi = qw + l15;
        const int kend = qw + 16;

        short8 qf0 = *(const short8*)(Qp + (size_t)(qw + l15) * DD + l4 * 8);
        short8 qf1 = *(const short8*)(Qp + (size_t)(qw + l15) * DD + 32 + l4 * 8);

        f32x4 ot[4];
#pragma unroll
        for (int c = 0; c < 4; ++c) ot[c] = (f32x4){0.f, 0.f, 0.f, 0.f};
        float m = -1e30f, lsum = 0.f;

#pragma unroll 1
        for (int kb = h * 64; kb < kend; kb += 256) {
            // QK^T in two K-halves (lower VGPR peak)
            f32x4 st[4];
            __builtin_amdgcn_s_setprio(1);
#pragma unroll
            for (int half = 0; half < 2; ++half) {
#pragma unroll
                for (int t = 0; t < 2; ++t) {
                    const unsigned short* kr =
                        Kp + (size_t)(kb + half * 32 + t * 16 + l15) * DD + l4 * 8;
                    short8 kfa = *(const short8*)(kr);
                    short8 kfb = *(const short8*)(kr + 32);
                    f32x4 z = (f32x4){0.f, 0.f, 0.f, 0.f};
                    z = __builtin_amdgcn_mfma_f32_16x16x32_bf16(kfa, qf0, z, 0, 0, 0);
                    z = __builtin_amdgcn_mfma_f32_16x16x32_bf16(kfb, qf1, z, 0, 0, 0);
                    st[half * 2 + t] = z;
                }
            }
            __builtin_amdgcn_s_setprio(0);
            // V fragments: issue now, consumed after softmax
            short8 vf[4][2];
#pragma unroll
            for (int c = 0; c < 4; ++c)
#pragma unroll
                for (int ch = 0; ch < 2; ++ch)
                    vf[c][ch] = *(const short8*)(Vp + (size_t)(c * 16 + l15) * TT
                                                 + kb + ch * 32 + l4 * 8);
            // causal mask only on the diagonal iteration (uniform test)
            if (!(kb + 63 <= qw)) {
#pragma unroll
                for (int t = 0; t < 4; ++t)
#pragma unroll
                    for (int r = 0; r < 4; ++r) {
                        const int kpos = kb + t * 16 + l4 * 4 + r;
                        st[t][r] = (kpos > qi) ? -30000.f : st[t][r];
                    }
            }
            // tree max over 16 values (depth 4), then 4-lane-group reduce
            float mx01 = fmaxf(fmaxf(st[0][0], st[0][1]), fmaxf(st[0][2], st[0][3]));
            float mx23 = fmaxf(fmaxf(st[1][0], st[1][1]), fmaxf(st[1][2], st[1][3]));
            float mx45 = fmaxf(fmaxf(st[2][0], st[2][1]), fmaxf(st[2][2], st[2][3]));
            float mx67 = fmaxf(fmaxf(st[3][0], st[3][1]), fmaxf(st[3][2], st[3][3]));
            float tmax = fmaxf(fmaxf(mx01, mx23), fmaxf(mx45, mx67));
            tmax = fmaxf(tmax, __shfl_xor(tmax, 16));
            tmax = fmaxf(tmax, __shfl_xor(tmax, 32));
            // T13 defer-max: skip rescale unless max grew past threshold
            if (!__all(tmax <= m + 8.f)) {
                const float mnew = fmaxf(m, tmax);
                const float corr = exp2_hw(m - mnew);
                lsum *= corr;
#pragma unroll
                for (int c = 0; c < 4; ++c) ot[c] *= corr;
                m = mnew;
            }
            // P = exp2(S - m), tree-sum, pack bf16
            float pv[16];
            u16x4 pw[4];
#pragma unroll
            for (int t = 0; t < 4; ++t)
#pragma unroll
                for (int r = 0; r < 4; ++r) {
                    float p = exp2_hw(st[t][r] - m);
                    pv[t * 4 + r] = p;
                    pw[t][r] = f2b(p);
                }
            float s0 = (pv[0] + pv[1]) + (pv[2] + pv[3]);
            float s1 = (pv[4] + pv[5]) + (pv[6] + pv[7]);
            float s2 = (pv[8] + pv[9]) + (pv[10] + pv[11]);
            float s3 = (pv[12] + pv[13]) + (pv[14] + pv[15]);
            lsum += (s0 + s1) + (s2 + s3);
            // P -> LDS (swizzled), read back as PV B-fragments
#pragma unroll
            for (int t = 0; t < 4; ++t)
                *(u16x4*)(prow + ((t * 32 + l4 * 8) ^ swz)) = pw[t];
            asm volatile("" ::: "memory");
            short8 pb0 = *(const short8*)(prow + ((l4 * 16) ^ swz));
            short8 pb1 = *(const short8*)(prow + ((64 + l4 * 16) ^ swz));
            asm volatile("" ::: "memory");
            __builtin_amdgcn_s_setprio(1);
#pragma unroll
            for (int c = 0; c < 4; ++c) {
                ot[c] = __builtin_amdgcn_mfma_f32_16x16x32_bf16(vf[c][0], pb0, ot[c], 0, 0, 0);
                ot[c] = __builtin_amdgcn_mfma_f32_16x16x32_bf16(vf[c][1], pb1, ot[c], 0, 0, 0);
            }
            __builtin_amdgcn_s_setprio(0);
        }

        // per-row denominator partial
        float ls = lsum + __shfl_xor(lsum, 16);
        ls += __shfl_xor(ls, 32);

        if (h > 0) {   // publish partial
            float* mb = &Mrg[h - 1][lane][0];
            mb[0] = m;
            mb[1] = ls;
#pragma unroll
            for (int c = 0; c < 4; ++c)
#pragma unroll
                for (int r = 0; r < 4; ++r) mb[2 + c * 4 + r] = ot[c][r];
        }
        __syncthreads();
        if (h == 0) {   // merge 4 partials, normalize, write over Q rows
            float mj[3], lj[3];
#pragma unroll
            for (int j = 0; j < 3; ++j) {
                mj[j] = Mrg[j][lane][0];
                lj[j] = Mrg[j][lane][1];
            }
            float mstar = fmaxf(fmaxf(m, mj[0]), fmaxf(mj[1], mj[2]));
            const float cs = exp2_hw(m - mstar);
            float cj[3];
            float den = ls * cs;
#pragma unroll
            for (int j = 0; j < 3; ++j) {
                cj[j] = exp2_hw(mj[j] - mstar);
                den += lj[j] * cj[j];
            }
            const float inv = 1.f / den;
#pragma unroll
            for (int c = 0; c < 4; ++c)
#pragma unroll
                for (int r = 0; r < 4; ++r) {
                    float v = ot[c][r] * cs;
#pragma unroll
                    for (int j = 0; j < 3; ++j)
                        v += Mrg[j][lane][2 + c * 4 + r] * cj[j];
                    v *= inv;
                    if (!finite_f(v)) v = 200.0f;   // canary
                    Olds[c * 16 + l4 * 4 + r][l15] = f2b(v);
                }
            asm volatile("" ::: "memory");
            const int q2 = lane >> 2, c8 = lane & 3;
#pragma unroll
            for (int s = 0; s < 2; ++s) {
                u16x8 o;
#pragma unroll
                for (int j = 0; j < 8; ++j) o[j] = Olds[s * 32 + c8 * 8 + j][q2];
                *(u16x8*)(Qp + (size_t)(qw + q2) * DD + s * 32 + c8 * 8) = o;
            }
        }
        __syncthreads();   // protect Mrg/Olds before next hv
    }
}

// -------- proj GEMM: Y([b][h][t][d] in Q region) @ WprojT + bias -> out fp32 --------
__global__ __launch_bounds__(256) void gemm_proj(const unsigned short* __restrict__ A,
                                                 const unsigned short* __restrict__ Bt,
                                                 const void* __restrict__ bias,
                                                 float* __restrict__ outO,
                                                 const int* __restrict__ flag) {
    __shared__ unsigned short As[128 * 32];
    __shared__ unsigned short Bs[128 * 32];
    const int Ksz = CCH;
    const int tid = threadIdx.x;
    const int lane = tid & 63;
    const int wid = tid >> 6;
    const int bm = blockIdx.y * 128;
    const int bn = blockIdx.x * 128;
    const int wm = (wid >> 1) * 64;
    const int wn = (wid & 1) * 64;
    const int sr = tid >> 2;
    const int sc = (tid & 3) * 8;
    const int l15 = lane & 15, l4 = lane >> 4;
    const int isb = *flag;

    f32x4 acc[4][4];
#pragma unroll
    for (int i = 0; i < 4; ++i)
#pragma unroll
        for (int j = 0; j < 4; ++j)
            acc[i][j] = (f32x4){0.f, 0.f, 0.f, 0.f};

    const int m0 = bm + sr;
    const unsigned short* Ar0 = A + (size_t)(m0 >> 11) * (HH * TT * DD)
                                  + (size_t)(m0 & 2047) * DD;
    const unsigned short* Ar1 = Ar0 + (size_t)64 * DD;
    const unsigned short* pb0 = Bt + (size_t)(bn + sr) * Ksz + sc;
    const unsigned short* pb1 = pb0 + (size_t)64 * Ksz;

    auto aoff = [&](int kt) -> size_t {
        return (size_t)(kt >> 6) * (TT * DD) + (kt & 32) + sc;
    };

    u16x8 a0 = *(const u16x8*)(Ar0 + aoff(0));
    u16x8 a1 = *(const u16x8*)(Ar1 + aoff(0));
    u16x8 b0 = *(const u16x8*)(pb0);
    u16x8 b1 = *(const u16x8*)(pb1);

    for (int kt = 0; kt < Ksz; kt += 32) {
        __syncthreads();
        *(u16x8*)&As[sr * 32 + sc] = a0;
        *(u16x8*)&As[(sr + 64) * 32 + sc] = a1;
        *(u16x8*)&Bs[sr * 32 + sc] = b0;
        *(u16x8*)&Bs[(sr + 64) * 32 + sc] = b1;
        if (kt + 32 < Ksz) {
            a0 = *(const u16x8*)(Ar0 + aoff(kt + 32));
            a1 = *(const u16x8*)(Ar1 + aoff(kt + 32));
            b0 = *(const u16x8*)(pb0 + kt + 32);
            b1 = *(const u16x8*)(pb1 + kt + 32);
        }
        __syncthreads();
        short8 af[4], bfr[4];
#pragma unroll
        for (int mi = 0; mi < 4; ++mi)
            af[mi] = *(const short8*)&As[(wm + mi * 16 + l15) * 32 + l4 * 8];
#pragma unroll
        for (int ni = 0; ni < 4; ++ni)
            bfr[ni] = *(const short8*)&Bs[(wn + ni * 16 + l15) * 32 + l4 * 8];
#pragma unroll
        for (int mi = 0; mi < 4; ++mi)
#pragma unroll
            for (int ni = 0; ni < 4; ++ni)
                acc[mi][ni] = __builtin_amdgcn_mfma_f32_16x16x32_bf16(
                    af[mi], bfr[ni], acc[mi][ni], 0, 0, 0);
    }

#pragma unroll
    for (int mi = 0; mi < 4; ++mi) {
#pragma unroll
        for (int ni = 0; ni < 4; ++ni) {
            const int col = bn + wn + ni * 16 + l15;
            const float bv = isb ? b2f(((const unsigned short*)bias)[col])
                                 : ((const float*)bias)[col];
#pragma unroll
            for (int r = 0; r < 4; ++r) {
                const int row = bm + wm + mi * 16 + l4 * 4 + r;
                float v = acc[mi][ni][r] + bv;
                if (!finite_f(v)) v = 300.0f;   // canary
                outO[(size_t)row * CCH + col] = v;
            }
        }
    }
}

extern "C" void kernel_launch(void* const* d_in, const int* in_sizes, int n_in,
                              void* d_out, int out_size, void* d_ws, size_t ws_size,
                              hipStream_t stream) {
    const void* x     = d_in[0];
    const void* Wqkv  = d_in[1];
    const void* bqkv  = d_in[2];
    const void* Wproj = d_in[3];
    const void* bproj = d_in[4];
    float* out = (float*)d_out;

    char* w = (char*)d_ws;
    int* flag = (int*)w;                          w += 256;
    unsigned short* wqkvT  = (unsigned short*)w;  w += (size_t)3 * CCH * CCH * 2;
    unsigned short* wprojT = (unsigned short*)w;  w += (size_t)CCH * CCH * 2;
    unsigned short* Qb     = (unsigned short*)w;  w += (size_t)MM * CCH * 2;
    unsigned short* Kb     = (unsigned short*)w;  w += (size_t)MM * CCH * 2;
    unsigned short* VTb    = (unsigned short*)w;  w += (size_t)MM * CCH * 2;
    unsigned short* Vstage = (unsigned short*)d_out;  // d_out as V scratch

    detect_k<<<1, 64, 0, stream>>>((const unsigned int*)x, flag);
    wtrans_k<<<dim3(96, 32), 256, 0, stream>>>(Wqkv, wqkvT, CCH, 3 * CCH, flag);
    wtrans_k<<<dim3(32, 32), 256, 0, stream>>>(Wproj, wprojT, CCH, CCH, flag);
    gemm_qkv<<<dim3(24, 64), 256, 0, stream>>>(x, wqkvT, bqkv, Qb, Kb, Vstage, flag);
    vtrans_k<<<dim3(32, 64), 256, 0, stream>>>(Vstage, VTb);
    attn_k<<<4096, 256, 0, stream>>>(Qb, Kb, VTb);          // writes Y over Q rows
    gemm_proj<<<dim3(8, 64), 256, 0, stream>>>(Qb, wprojT, bproj, out, flag);
}

// Round 11
// 297.943 us; speedup vs baseline: 1.9042x; 1.3231x over previous
//
#include <hip/hip_runtime.h>
#include <hip/hip_bf16.h>

#define TT 2048
#define CCH 1024
#define HH 16
#define DD 64
#define BB 4
#define MM (BB*TT)

typedef __attribute__((ext_vector_type(4))) float f32x4;
typedef __attribute__((ext_vector_type(8))) short short8;
typedef __attribute__((ext_vector_type(8))) unsigned short u16x8;
typedef __attribute__((ext_vector_type(4))) unsigned short u16x4;

__device__ __forceinline__ unsigned short f2b(float f) {
    unsigned int u = __float_as_uint(f);
    u += 0x7fffu + ((u >> 16) & 1u);
    return (unsigned short)(u >> 16);
}
__device__ __forceinline__ float b2f(unsigned short u) {
    return __uint_as_float(((unsigned int)u) << 16);
}
__device__ __forceinline__ int finite_f(float v) {
    return ((__float_as_uint(v) >> 23) & 0xFFu) != 0xFFu;
}
__device__ __forceinline__ float exp2_hw(float x) {
    return __builtin_amdgcn_exp2f(x);
}

// ---------------- input-dtype detector ----------------
__global__ __launch_bounds__(64) void detect_k(const unsigned int* __restrict__ x,
                                               int* __restrict__ flag) {
    int tid = threadIdx.x;
    int cnt = 0;
#pragma unroll
    for (int i = 0; i < 16; ++i) {
        unsigned int w = x[tid * 16 + i];
        unsigned int lo = w & 0xFFFFu;
        unsigned int e = (lo >> 7) & 0xFFu;
        if ((e >= 0x62u && e <= 0x90u) || lo == 0u) ++cnt;
    }
#pragma unroll
    for (int o = 32; o; o >>= 1) cnt += __shfl_down(cnt, o);
    if (tid == 0) *flag = (cnt >= 640) ? 1 : 0;
}

// ------------- W transpose(+cast): [R][Cc] -> bf16 [Cc][R] -------------
__global__ __launch_bounds__(256) void wtrans_k(const void* __restrict__ in,
                                                unsigned short* __restrict__ out,
                                                int R, int Cc,
                                                const int* __restrict__ flag) {
    __shared__ float tile[32][33];
    const int tid = threadIdx.x;
    const int c0 = blockIdx.x * 32, r0 = blockIdx.y * 32;
    const int isb = *flag;
#pragma unroll
    for (int i = 0; i < 4; ++i) {
        int e = i * 256 + tid;
        int row = e >> 5, col = e & 31;
        size_t idx = (size_t)(r0 + row) * Cc + (c0 + col);
        tile[row][col] = isb ? b2f(((const unsigned short*)in)[idx])
                             : ((const float*)in)[idx];
    }
    __syncthreads();
#pragma unroll
    for (int i = 0; i < 4; ++i) {
        int e = i * 256 + tid;
        int crow = e >> 5, rcol = e & 31;
        out[(size_t)(c0 + crow) * R + (r0 + rcol)] = f2b(tile[rcol][crow]);
    }
}

// ------------- V transpose: bf16 [bh][2048][64] -> [bh][64][2048] -------------
__global__ __launch_bounds__(256) void vtrans_k(const unsigned short* __restrict__ V,
                                                unsigned short* __restrict__ VT) {
    __shared__ unsigned short tile[64][68];
    const int tid = threadIdx.x;
    const int t0 = blockIdx.x * 64;
    const int bh = blockIdx.y;
    const unsigned short* in = V + ((size_t)bh * TT + t0) * DD;
#pragma unroll
    for (int i = 0; i < 4; ++i) {
        int cid = i * 256 + tid;
        int row = cid >> 4;
        int ch  = cid & 15;
        u16x4 v = *(const u16x4*)(in + row * DD + ch * 4);
        *(u16x4*)&tile[row][ch * 4] = v;
    }
    __syncthreads();
    unsigned short* out = VT + (size_t)bh * DD * TT + t0;
#pragma unroll
    for (int i = 0; i < 4; ++i) {
        int cid = i * 256 + tid;
        int drow = cid >> 4;
        int tch  = cid & 15;
        u16x4 v;
        v[0] = tile[tch * 4 + 0][drow];
        v[1] = tile[tch * 4 + 1][drow];
        v[2] = tile[tch * 4 + 2][drow];
        v[3] = tile[tch * 4 + 3][drow];
        *(u16x4*)(out + (size_t)drow * TT + tch * 4) = v;
    }
}

// -------- QKV GEMM: x[M][K] (fp32|bf16) @ WqkvT[N][K] bf16 + bias --------
__global__ __launch_bounds__(256) void gemm_qkv(const void* __restrict__ x,
                                                const unsigned short* __restrict__ Bt,
                                                const void* __restrict__ bias,
                                                unsigned short* __restrict__ outQ,
                                                unsigned short* __restrict__ outK,
                                                unsigned short* __restrict__ outV,
                                                const int* __restrict__ flag) {
    __shared__ unsigned short As[128 * 32];
    __shared__ unsigned short Bs[128 * 32];
    const int Ksz = CCH;
    const int tid = threadIdx.x;
    const int lane = tid & 63;
    const int wid = tid >> 6;
    const int bm = blockIdx.y * 128;
    const int bn = blockIdx.x * 128;
    const int wm = (wid >> 1) * 64;
    const int wn = (wid & 1) * 64;
    const int sr = tid >> 2;
    const int sc = (tid & 3) * 8;
    const int l15 = lane & 15, l4 = lane >> 4;
    const int isb = *flag;

    f32x4 acc[4][4];
#pragma unroll
    for (int i = 0; i < 4; ++i)
#pragma unroll
        for (int j = 0; j < 4; ++j)
            acc[i][j] = (f32x4){0.f, 0.f, 0.f, 0.f};

    const size_t aoff0 = (size_t)(bm + sr) * Ksz + sc;
    const size_t aoff1 = aoff0 + (size_t)64 * Ksz;
    const unsigned short* pb0 = Bt + (size_t)(bn + sr) * Ksz + sc;
    const unsigned short* pb1 = pb0 + (size_t)64 * Ksz;

    auto lda = [&](size_t off) -> u16x8 {
        if (isb) return *(const u16x8*)((const unsigned short*)x + off);
        const float4* p = (const float4*)((const float*)x + off);
        float4 v0 = p[0], v1 = p[1];
        u16x8 o;
        o[0] = f2b(v0.x); o[1] = f2b(v0.y); o[2] = f2b(v0.z); o[3] = f2b(v0.w);
        o[4] = f2b(v1.x); o[5] = f2b(v1.y); o[6] = f2b(v1.z); o[7] = f2b(v1.w);
        return o;
    };

    u16x8 a0 = lda(aoff0);
    u16x8 a1 = lda(aoff1);
    u16x8 b0 = *(const u16x8*)(pb0);
    u16x8 b1 = *(const u16x8*)(pb1);

    for (int kt = 0; kt < Ksz; kt += 32) {
        __syncthreads();
        *(u16x8*)&As[sr * 32 + sc] = a0;
        *(u16x8*)&As[(sr + 64) * 32 + sc] = a1;
        *(u16x8*)&Bs[sr * 32 + sc] = b0;
        *(u16x8*)&Bs[(sr + 64) * 32 + sc] = b1;
        if (kt + 32 < Ksz) {
            a0 = lda(aoff0 + kt + 32);
            a1 = lda(aoff1 + kt + 32);
            b0 = *(const u16x8*)(pb0 + kt + 32);
            b1 = *(const u16x8*)(pb1 + kt + 32);
        }
        __syncthreads();
        short8 af[4], bfr[4];
#pragma unroll
        for (int mi = 0; mi < 4; ++mi)
            af[mi] = *(const short8*)&As[(wm + mi * 16 + l15) * 32 + l4 * 8];
#pragma unroll
        for (int ni = 0; ni < 4; ++ni)
            bfr[ni] = *(const short8*)&Bs[(wn + ni * 16 + l15) * 32 + l4 * 8];
#pragma unroll
        for (int mi = 0; mi < 4; ++mi)
#pragma unroll
            for (int ni = 0; ni < 4; ++ni)
                acc[mi][ni] = __builtin_amdgcn_mfma_f32_16x16x32_bf16(
                    af[mi], bfr[ni], acc[mi][ni], 0, 0, 0);
    }

#pragma unroll
    for (int mi = 0; mi < 4; ++mi) {
#pragma unroll
        for (int ni = 0; ni < 4; ++ni) {
            const int col = bn + wn + ni * 16 + l15;
            const float bv = isb ? b2f(((const unsigned short*)bias)[col])
                                 : ((const float*)bias)[col];
#pragma unroll
            for (int r = 0; r < 4; ++r) {
                const int row = bm + wm + mi * 16 + l4 * 4 + r;
                float v = acc[mi][ni][r] + bv;
                const int which = col >> 10;
                const int h = (col >> 6) & 15;
                const int d = col & 63;
                const int b = row >> 11, t = row & 2047;
                const size_t idx = (((size_t)b * HH + h) * TT + t) * DD + d;
                if (which == 0)      outQ[idx] = f2b(v * 0.18033688f);  // /sqrt(64)*log2e
                else if (which == 1) outK[idx] = f2b(v);
                else                 outV[idx] = f2b(v);
            }
        }
    }
}

// ---------------- flash attention v5: 32-q-row waves, shared K/V ----------------
// Block (4 waves) owns ONE 32-row q-tile pair {qt,63-qt} (hv loop). Within a
// tile, the 4 waves split the KV range mod-4 (KVBLK=64). Each wave computes
// TWO 16-row subtiles (A,B) sharing each K/V load -> half the iterations of
// round 10 at ~same chain length. Partials merged in LDS (union'd buffers).
__global__ __launch_bounds__(256) void attn_k(unsigned short* __restrict__ Q,
                                              const unsigned short* __restrict__ K,
                                              const unsigned short* __restrict__ VT) {
    // union: main loop uses Plds [4 waves][32][64] (16 KB);
    // epilogue uses Mrg [3][64][36] f32 (27.6 KB) + Olds [64][34] u16 (4.3 KB)
    __shared__ __align__(16) char shmem[32000];
    const int tid = threadIdx.x, lane = tid & 63, h = tid >> 6;
    const int bid = blockIdx.x;
    const int swb = (bid & 7) * 256 + (bid >> 3);   // XCD swizzle (2048%8==0)
    const int bh = swb >> 5;                    // 0..63
    const int pair = swb & 31;                  // 0..31
    const int l15 = lane & 15, l4 = lane >> 4;
    unsigned short* Qp = Q + (size_t)bh * TT * DD;
    const unsigned short* Kp = K + (size_t)bh * TT * DD;
    const unsigned short* Vp = VT + (size_t)bh * DD * TT;
    const int swz = (l15 & 7) << 4;
    unsigned short (*PldsW)[64] = (unsigned short (*)[64])(shmem + h * 4096);
    unsigned char* prowA = (unsigned char*)&PldsW[l15][0];
    unsigned char* prowB = (unsigned char*)&PldsW[16 + l15][0];
    float* MrgF = (float*)shmem;
    unsigned short (*Olds)[34] = (unsigned short (*)[34])(shmem + 27648);

#pragma unroll 1
    for (int hv = 0; hv < 2; ++hv) {
        const int qt = hv ? (63 - pair) : pair;      // 32-row tile index 0..63
        const int qw = qt << 5;
        const int qiA = qw + l15, qiB = qw + 16 + l15;
        const int kend = qw + 32;

        short8 qfA0 = *(const short8*)(Qp + (size_t)(qw + l15) * DD + l4 * 8);
        short8 qfA1 = *(const short8*)(Qp + (size_t)(qw + l15) * DD + 32 + l4 * 8);
        short8 qfB0 = *(const short8*)(Qp + (size_t)(qw + 16 + l15) * DD + l4 * 8);
        short8 qfB1 = *(const short8*)(Qp + (size_t)(qw + 16 + l15) * DD + 32 + l4 * 8);

        f32x4 otA[4], otB[4];
#pragma unroll
        for (int c = 0; c < 4; ++c) {
            otA[c] = (f32x4){0.f, 0.f, 0.f, 0.f};
            otB[c] = (f32x4){0.f, 0.f, 0.f, 0.f};
        }
        float mA = -1e30f, lA = 0.f, mB = -1e30f, lB = 0.f;

        // softmax over one 16-row subtile's 64-kpos scores
        auto softmax16 = [&](f32x4 (&st)[4], float& m, float& lsum, f32x4 (&ot)[4],
                             int qi, bool needMask, int kb, unsigned char* prow) {
            if (needMask) {
#pragma unroll
                for (int t = 0; t < 4; ++t)
#pragma unroll
                    for (int r = 0; r < 4; ++r) {
                        const int kpos = kb + t * 16 + l4 * 4 + r;
                        st[t][r] = (kpos > qi) ? -30000.f : st[t][r];
                    }
            }
            float mx0 = fmaxf(fmaxf(st[0][0], st[0][1]), fmaxf(st[0][2], st[0][3]));
            float mx1 = fmaxf(fmaxf(st[1][0], st[1][1]), fmaxf(st[1][2], st[1][3]));
            float mx2 = fmaxf(fmaxf(st[2][0], st[2][1]), fmaxf(st[2][2], st[2][3]));
            float mx3 = fmaxf(fmaxf(st[3][0], st[3][1]), fmaxf(st[3][2], st[3][3]));
            float tmax = fmaxf(fmaxf(mx0, mx1), fmaxf(mx2, mx3));
            tmax = fmaxf(tmax, __shfl_xor(tmax, 16));
            tmax = fmaxf(tmax, __shfl_xor(tmax, 32));
            if (!__all(tmax <= m + 8.f)) {       // T13 defer-max
                const float mnew = fmaxf(m, tmax);
                const float corr = exp2_hw(m - mnew);
                lsum *= corr;
#pragma unroll
                for (int c = 0; c < 4; ++c) ot[c] *= corr;
                m = mnew;
            }
            u16x4 pw[4];
            float s0 = 0.f, s1 = 0.f, s2 = 0.f, s3 = 0.f;
#pragma unroll
            for (int t = 0; t < 4; ++t)
#pragma unroll
                for (int r = 0; r < 4; ++r) {
                    float p = exp2_hw(st[t][r] - m);
                    if (t == 0) s0 += p; else if (t == 1) s1 += p;
                    else if (t == 2) s2 += p; else s3 += p;
                    pw[t][r] = f2b(p);
                }
            lsum += (s0 + s1) + (s2 + s3);
#pragma unroll
            for (int t = 0; t < 4; ++t)
                *(u16x4*)(prow + ((t * 32 + l4 * 8) ^ swz)) = pw[t];
        };

#pragma unroll 1
        for (int kb = h * 64; kb < kend; kb += 256) {
            // K fragments (shared by both subtiles)
            short8 kf[4][2];
#pragma unroll
            for (int t = 0; t < 4; ++t) {
                const unsigned short* kr = Kp + (size_t)(kb + t * 16 + l15) * DD + l4 * 8;
                kf[t][0] = *(const short8*)(kr);
                kf[t][1] = *(const short8*)(kr + 32);
            }
            // V fragments (shared) — issue early, consumed after softmax
            short8 vf[4][2];
#pragma unroll
            for (int c = 0; c < 4; ++c)
#pragma unroll
                for (int ch = 0; ch < 2; ++ch)
                    vf[c][ch] = *(const short8*)(Vp + (size_t)(c * 16 + l15) * TT
                                                 + kb + ch * 32 + l4 * 8);
            // QK^T subtile A
            f32x4 st[4];
            __builtin_amdgcn_s_setprio(1);
#pragma unroll
            for (int t = 0; t < 4; ++t) {
                f32x4 z = (f32x4){0.f, 0.f, 0.f, 0.f};
                z = __builtin_amdgcn_mfma_f32_16x16x32_bf16(kf[t][0], qfA0, z, 0, 0, 0);
                z = __builtin_amdgcn_mfma_f32_16x16x32_bf16(kf[t][1], qfA1, z, 0, 0, 0);
                st[t] = z;
            }
            __builtin_amdgcn_s_setprio(0);
            softmax16(st, mA, lA, otA, qiA, kb + 63 > qw, kb, prowA);
            // QK^T subtile B (reuses kf)
            __builtin_amdgcn_s_setprio(1);
#pragma unroll
            for (int t = 0; t < 4; ++t) {
                f32x4 z = (f32x4){0.f, 0.f, 0.f, 0.f};
                z = __builtin_amdgcn_mfma_f32_16x16x32_bf16(kf[t][0], qfB0, z, 0, 0, 0);
                z = __builtin_amdgcn_mfma_f32_16x16x32_bf16(kf[t][1], qfB1, z, 0, 0, 0);
                st[t] = z;
            }
            __builtin_amdgcn_s_setprio(0);
            softmax16(st, mB, lB, otB, qiB, kb + 63 > qw + 16, kb, prowB);
            // read both P blocks back as PV B-fragments
            asm volatile("" ::: "memory");
            short8 pbA0 = *(const short8*)(prowA + ((l4 * 16) ^ swz));
            short8 pbA1 = *(const short8*)(prowA + ((64 + l4 * 16) ^ swz));
            short8 pbB0 = *(const short8*)(prowB + ((l4 * 16) ^ swz));
            short8 pbB1 = *(const short8*)(prowB + ((64 + l4 * 16) ^ swz));
            asm volatile("" ::: "memory");
            __builtin_amdgcn_s_setprio(1);
#pragma unroll
            for (int c = 0; c < 4; ++c) {
                otA[c] = __builtin_amdgcn_mfma_f32_16x16x32_bf16(vf[c][0], pbA0, otA[c], 0, 0, 0);
                otA[c] = __builtin_amdgcn_mfma_f32_16x16x32_bf16(vf[c][1], pbA1, otA[c], 0, 0, 0);
                otB[c] = __builtin_amdgcn_mfma_f32_16x16x32_bf16(vf[c][0], pbB0, otB[c], 0, 0, 0);
                otB[c] = __builtin_amdgcn_mfma_f32_16x16x32_bf16(vf[c][1], pbB1, otB[c], 0, 0, 0);
            }
            __builtin_amdgcn_s_setprio(0);
        }

        // per-row denominator partials (sum the 4 l4-groups)
        float lsA = lA + __shfl_xor(lA, 16);
        lsA += __shfl_xor(lsA, 32);
        float lsB = lB + __shfl_xor(lB, 16);
        lsB += __shfl_xor(lsB, 32);

        __syncthreads();   // all waves done with Plds -> safe to alias as Mrg
        if (h > 0) {
            float* mb = MrgF + ((size_t)(h - 1) * 64 + lane) * 36;
            mb[0] = mA; mb[1] = lsA; mb[2] = mB; mb[3] = lsB;
#pragma unroll
            for (int c = 0; c < 4; ++c)
#pragma unroll
                for (int r = 0; r < 4; ++r) {
                    mb[4 + c * 4 + r]  = otA[c][r];
                    mb[20 + c * 4 + r] = otB[c][r];
                }
        }
        __syncthreads();
        if (h == 0) {
            // merge one subtile's 4 partials and deposit bf16 into Olds
            auto merge16 = [&](float m0, float ls0, const f32x4 (&ot)[4],
                               int mOff, int oOff, int col) {
                float mj[3], lj[3];
                float mstar = m0;
#pragma unroll
                for (int j = 0; j < 3; ++j) {
                    mj[j] = MrgF[((size_t)j * 64 + lane) * 36 + mOff];
                    lj[j] = MrgF[((size_t)j * 64 + lane) * 36 + mOff + 1];
                    mstar = fmaxf(mstar, mj[j]);
                }
                const float cs = exp2_hw(m0 - mstar);
                float cj[3];
                float den = ls0 * cs;
#pragma unroll
                for (int j = 0; j < 3; ++j) {
                    cj[j] = exp2_hw(mj[j] - mstar);
                    den += lj[j] * cj[j];
                }
                const float inv = 1.f / den;
#pragma unroll
                for (int c = 0; c < 4; ++c)
#pragma unroll
                    for (int r = 0; r < 4; ++r) {
                        float v = ot[c][r] * cs;
#pragma unroll
                        for (int j = 0; j < 3; ++j)
                            v += MrgF[((size_t)j * 64 + lane) * 36 + oOff + c * 4 + r] * cj[j];
                        v *= inv;
                        if (!finite_f(v)) v = 200.0f;   // canary
                        Olds[c * 16 + l4 * 4 + r][col] = f2b(v);
                    }
            };
            merge16(mA, lsA, otA, 0, 4, l15);
            merge16(mB, lsB, otB, 2, 20, 16 + l15);
            asm volatile("" ::: "memory");
            // transpose-write 32 rows x 64 d over this tile's Q rows
            const int qr = lane >> 1, hf = lane & 1;
#pragma unroll
            for (int chunk = 0; chunk < 4; ++chunk) {
                u16x8 o;
#pragma unroll
                for (int j = 0; j < 8; ++j) o[j] = Olds[hf * 32 + chunk * 8 + j][qr];
                *(u16x8*)(Qp + (size_t)(qw + qr) * DD + hf * 32 + chunk * 8) = o;
            }
        }
        __syncthreads();   // protect union'd shmem before next hv
    }
}

// -------- proj GEMM: Y([b][h][t][d] in Q region) @ WprojT + bias -> out fp32 --------
__global__ __launch_bounds__(256) void gemm_proj(const unsigned short* __restrict__ A,
                                                 const unsigned short* __restrict__ Bt,
                                                 const void* __restrict__ bias,
                                                 float* __restrict__ outO,
                                                 const int* __restrict__ flag) {
    __shared__ unsigned short As[128 * 32];
    __shared__ unsigned short Bs[128 * 32];
    const int Ksz = CCH;
    const int tid = threadIdx.x;
    const int lane = tid & 63;
    const int wid = tid >> 6;
    const int bm = blockIdx.y * 128;
    const int bn = blockIdx.x * 128;
    const int wm = (wid >> 1) * 64;
    const int wn = (wid & 1) * 64;
    const int sr = tid >> 2;
    const int sc = (tid & 3) * 8;
    const int l15 = lane & 15, l4 = lane >> 4;
    const int isb = *flag;

    f32x4 acc[4][4];
#pragma unroll
    for (int i = 0; i < 4; ++i)
#pragma unroll
        for (int j = 0; j < 4; ++j)
            acc[i][j] = (f32x4){0.f, 0.f, 0.f, 0.f};

    const int m0 = bm + sr;
    const unsigned short* Ar0 = A + (size_t)(m0 >> 11) * (HH * TT * DD)
                                  + (size_t)(m0 & 2047) * DD;
    const unsigned short* Ar1 = Ar0 + (size_t)64 * DD;
    const unsigned short* pb0 = Bt + (size_t)(bn + sr) * Ksz + sc;
    const unsigned short* pb1 = pb0 + (size_t)64 * Ksz;

    auto aoff = [&](int kt) -> size_t {
        return (size_t)(kt >> 6) * (TT * DD) + (kt & 32) + sc;
    };

    u16x8 a0 = *(const u16x8*)(Ar0 + aoff(0));
    u16x8 a1 = *(const u16x8*)(Ar1 + aoff(0));
    u16x8 b0 = *(const u16x8*)(pb0);
    u16x8 b1 = *(const u16x8*)(pb1);

    for (int kt = 0; kt < Ksz; kt += 32) {
        __syncthreads();
        *(u16x8*)&As[sr * 32 + sc] = a0;
        *(u16x8*)&As[(sr + 64) * 32 + sc] = a1;
        *(u16x8*)&Bs[sr * 32 + sc] = b0;
        *(u16x8*)&Bs[(sr + 64) * 32 + sc] = b1;
        if (kt + 32 < Ksz) {
            a0 = *(const u16x8*)(Ar0 + aoff(kt + 32));
            a1 = *(const u16x8*)(Ar1 + aoff(kt + 32));
            b0 = *(const u16x8*)(pb0 + kt + 32);
            b1 = *(const u16x8*)(pb1 + kt + 32);
        }
        __syncthreads();
        short8 af[4], bfr[4];
#pragma unroll
        for (int mi = 0; mi < 4; ++mi)
            af[mi] = *(const short8*)&As[(wm + mi * 16 + l15) * 32 + l4 * 8];
#pragma unroll
        for (int ni = 0; ni < 4; ++ni)
            bfr[ni] = *(const short8*)&Bs[(wn + ni * 16 + l15) * 32 + l4 * 8];
#pragma unroll
        for (int mi = 0; mi < 4; ++mi)
#pragma unroll
            for (int ni = 0; ni < 4; ++ni)
                acc[mi][ni] = __builtin_amdgcn_mfma_f32_16x16x32_bf16(
                    af[mi], bfr[ni], acc[mi][ni], 0, 0, 0);
    }

#pragma unroll
    for (int mi = 0; mi < 4; ++mi) {
#pragma unroll
        for (int ni = 0; ni < 4; ++ni) {
            const int col = bn + wn + ni * 16 + l15;
            const float bv = isb ? b2f(((const unsigned short*)bias)[col])
                                 : ((const float*)bias)[col];
#pragma unroll
            for (int r = 0; r < 4; ++r) {
                const int row = bm + wm + mi * 16 + l4 * 4 + r;
                float v = acc[mi][ni][r] + bv;
                if (!finite_f(v)) v = 300.0f;   // canary
                outO[(size_t)row * CCH + col] = v;
            }
        }
    }
}

extern "C" void kernel_launch(void* const* d_in, const int* in_sizes, int n_in,
                              void* d_out, int out_size, void* d_ws, size_t ws_size,
                              hipStream_t stream) {
    const void* x     = d_in[0];
    const void* Wqkv  = d_in[1];
    const void* bqkv  = d_in[2];
    const void* Wproj = d_in[3];
    const void* bproj = d_in[4];
    float* out = (float*)d_out;

    char* w = (char*)d_ws;
    int* flag = (int*)w;                          w += 256;
    unsigned short* wqkvT  = (unsigned short*)w;  w += (size_t)3 * CCH * CCH * 2;
    unsigned short* wprojT = (unsigned short*)w;  w += (size_t)CCH * CCH * 2;
    unsigned short* Qb     = (unsigned short*)w;  w += (size_t)MM * CCH * 2;
    unsigned short* Kb     = (unsigned short*)w;  w += (size_t)MM * CCH * 2;
    unsigned short* VTb    = (unsigned short*)w;  w += (size_t)MM * CCH * 2;
    unsigned short* Vstage = (unsigned short*)d_out;  // d_out as V scratch

    detect_k<<<1, 64, 0, stream>>>((const unsigned int*)x, flag);
    wtrans_k<<<dim3(96, 32), 256, 0, stream>>>(Wqkv, wqkvT, CCH, 3 * CCH, flag);
    wtrans_k<<<dim3(32, 32), 256, 0, stream>>>(Wproj, wprojT, CCH, CCH, flag);
    gemm_qkv<<<dim3(24, 64), 256, 0, stream>>>(x, wqkvT, bqkv, Qb, Kb, Vstage, flag);
    vtrans_k<<<dim3(32, 64), 256, 0, stream>>>(Vstage, VTb);
    attn_k<<<2048, 256, 0, stream>>>(Qb, Kb, VTb);          // writes Y over Q rows
    gemm_proj<<<dim3(8, 64), 256, 0, stream>>>(Qb, wprojT, bproj, out, flag);
}

// Round 12
// 278.813 us; speedup vs baseline: 2.0349x; 1.0686x over previous
//
#include <hip/hip_runtime.h>
#include <hip/hip_bf16.h>

#define TT 2048
#define CCH 1024
#define HH 16
#define DD 64
#define BB 4
#define MM (BB*TT)

typedef __attribute__((ext_vector_type(4))) float f32x4;
typedef __attribute__((ext_vector_type(8))) short short8;
typedef __attribute__((ext_vector_type(8))) unsigned short u16x8;
typedef __attribute__((ext_vector_type(4))) unsigned short u16x4;

__device__ __forceinline__ unsigned short f2b(float f) {
    unsigned int u = __float_as_uint(f);
    u += 0x7fffu + ((u >> 16) & 1u);
    return (unsigned short)(u >> 16);
}
__device__ __forceinline__ float b2f(unsigned short u) {
    return __uint_as_float(((unsigned int)u) << 16);
}
__device__ __forceinline__ int finite_f(float v) {
    return ((__float_as_uint(v) >> 23) & 0xFFu) != 0xFFu;
}
__device__ __forceinline__ float exp2_hw(float x) {
    return __builtin_amdgcn_exp2f(x);
}

// async global->LDS, 16B per lane (dest must be wave-uniform base + lane*16)
typedef const __attribute__((address_space(1))) unsigned int g_u32;
typedef __attribute__((address_space(3))) unsigned int l_u32;
__device__ __forceinline__ void gl_lds16(const unsigned short* g, unsigned short* l) {
    __builtin_amdgcn_global_load_lds((g_u32*)g, (l_u32*)l, 16, 0, 0);
}

// ---------------- input-dtype detector ----------------
__global__ __launch_bounds__(64) void detect_k(const unsigned int* __restrict__ x,
                                               int* __restrict__ flag) {
    int tid = threadIdx.x;
    int cnt = 0;
#pragma unroll
    for (int i = 0; i < 16; ++i) {
        unsigned int w = x[tid * 16 + i];
        unsigned int lo = w & 0xFFFFu;
        unsigned int e = (lo >> 7) & 0xFFu;
        if ((e >= 0x62u && e <= 0x90u) || lo == 0u) ++cnt;
    }
#pragma unroll
    for (int o = 32; o; o >>= 1) cnt += __shfl_down(cnt, o);
    if (tid == 0) *flag = (cnt >= 640) ? 1 : 0;
}

// ---------------- cast/copy x -> bf16 ----------------
__global__ __launch_bounds__(256) void cast_x_k(const void* __restrict__ in,
                                                unsigned short* __restrict__ out,
                                                const int* __restrict__ flag) {
    int g = blockIdx.x * 256 + threadIdx.x;
    if (*flag) {
        *(u16x8*)(out + (size_t)g * 8) =
            *(const u16x8*)((const unsigned short*)in + (size_t)g * 8);
    } else {
        const float4* p = (const float4*)((const float*)in + (size_t)g * 8);
        float4 v0 = p[0], v1 = p[1];
        u16x8 o;
        o[0] = f2b(v0.x); o[1] = f2b(v0.y); o[2] = f2b(v0.z); o[3] = f2b(v0.w);
        o[4] = f2b(v1.x); o[5] = f2b(v1.y); o[6] = f2b(v1.z); o[7] = f2b(v1.w);
        *(u16x8*)(out + (size_t)g * 8) = o;
    }
}

// ------------- W transpose(+cast): [R][Cc] -> bf16 [Cc][R] -------------
__global__ __launch_bounds__(256) void wtrans_k(const void* __restrict__ in,
                                                unsigned short* __restrict__ out,
                                                int R, int Cc,
                                                const int* __restrict__ flag) {
    __shared__ float tile[32][33];
    const int tid = threadIdx.x;
    const int c0 = blockIdx.x * 32, r0 = blockIdx.y * 32;
    const int isb = *flag;
#pragma unroll
    for (int i = 0; i < 4; ++i) {
        int e = i * 256 + tid;
        int row = e >> 5, col = e & 31;
        size_t idx = (size_t)(r0 + row) * Cc + (c0 + col);
        tile[row][col] = isb ? b2f(((const unsigned short*)in)[idx])
                             : ((const float*)in)[idx];
    }
    __syncthreads();
#pragma unroll
    for (int i = 0; i < 4; ++i) {
        int e = i * 256 + tid;
        int crow = e >> 5, rcol = e & 31;
        out[(size_t)(c0 + crow) * R + (r0 + rcol)] = f2b(tile[rcol][crow]);
    }
}

// ------------- V transpose: bf16 [bh][2048][64] -> [bh][64][2048] -------------
__global__ __launch_bounds__(256) void vtrans_k(const unsigned short* __restrict__ V,
                                                unsigned short* __restrict__ VT) {
    __shared__ unsigned short tile[64][68];
    const int tid = threadIdx.x;
    const int t0 = blockIdx.x * 64;
    const int bh = blockIdx.y;
    const unsigned short* in = V + ((size_t)bh * TT + t0) * DD;
#pragma unroll
    for (int i = 0; i < 4; ++i) {
        int cid = i * 256 + tid;
        int row = cid >> 4;
        int ch  = cid & 15;
        u16x4 v = *(const u16x4*)(in + row * DD + ch * 4);
        *(u16x4*)&tile[row][ch * 4] = v;
    }
    __syncthreads();
    unsigned short* out = VT + (size_t)bh * DD * TT + t0;
#pragma unroll
    for (int i = 0; i < 4; ++i) {
        int cid = i * 256 + tid;
        int drow = cid >> 4;
        int tch  = cid & 15;
        u16x4 v;
        v[0] = tile[tch * 4 + 0][drow];
        v[1] = tile[tch * 4 + 1][drow];
        v[2] = tile[tch * 4 + 2][drow];
        v[3] = tile[tch * 4 + 3][drow];
        *(u16x4*)(out + (size_t)drow * TT + tch * 4) = v;
    }
}

// -------- QKV GEMM: xb[M][K] bf16 @ WqkvT[N][K] bf16 + bias --------
// global_load_lds staging (m97 structure). Scatter Q/K/V.
__global__ __launch_bounds__(256) void gemm_qkv(const unsigned short* __restrict__ A,
                                                const unsigned short* __restrict__ Bt,
                                                const void* __restrict__ bias,
                                                unsigned short* __restrict__ outQ,
                                                unsigned short* __restrict__ outK,
                                                unsigned short* __restrict__ outV,
                                                const int* __restrict__ flag) {
    __shared__ unsigned short As[128 * 32];
    __shared__ unsigned short Bs[128 * 32];
    const int Ksz = CCH;
    const int tid = threadIdx.x;
    const int lane = tid & 63;
    const int wid = tid >> 6;
    const int bm = blockIdx.y * 128;
    const int bn = blockIdx.x * 128;
    const int wm = (wid >> 1) * 64;
    const int wn = (wid & 1) * 64;
    const int sr = tid >> 2;
    const int sc = (tid & 3) * 8;
    const int l15 = lane & 15, l4 = lane >> 4;
    const int isb = *flag;

    f32x4 acc[4][4];
#pragma unroll
    for (int i = 0; i < 4; ++i)
#pragma unroll
        for (int j = 0; j < 4; ++j)
            acc[i][j] = (f32x4){0.f, 0.f, 0.f, 0.f};

    const unsigned short* pa0 = A + (size_t)(bm + sr) * Ksz + sc;
    const unsigned short* pa1 = pa0 + (size_t)64 * Ksz;
    const unsigned short* pb0 = Bt + (size_t)(bn + sr) * Ksz + sc;
    const unsigned short* pb1 = pb0 + (size_t)64 * Ksz;
    unsigned short* lA0 = &As[sr * 32 + sc];          // byte off = 16*tid
    unsigned short* lA1 = &As[(sr + 64) * 32 + sc];   // 16*tid + 4096
    unsigned short* lB0 = &Bs[sr * 32 + sc];
    unsigned short* lB1 = &Bs[(sr + 64) * 32 + sc];

    for (int kt = 0; kt < Ksz; kt += 32) {
        __syncthreads();   // WAR: all waves done reading previous tile
        gl_lds16(pa0 + kt, lA0);
        gl_lds16(pa1 + kt, lA1);
        gl_lds16(pb0 + kt, lB0);
        gl_lds16(pb1 + kt, lB1);
        __syncthreads();   // compiler drains vmcnt(0) before barrier -> LDS ready
        short8 af[4], bfr[4];
#pragma unroll
        for (int mi = 0; mi < 4; ++mi)
            af[mi] = *(const short8*)&As[(wm + mi * 16 + l15) * 32 + l4 * 8];
#pragma unroll
        for (int ni = 0; ni < 4; ++ni)
            bfr[ni] = *(const short8*)&Bs[(wn + ni * 16 + l15) * 32 + l4 * 8];
#pragma unroll
        for (int mi = 0; mi < 4; ++mi)
#pragma unroll
            for (int ni = 0; ni < 4; ++ni)
                acc[mi][ni] = __builtin_amdgcn_mfma_f32_16x16x32_bf16(
                    af[mi], bfr[ni], acc[mi][ni], 0, 0, 0);
    }

#pragma unroll
    for (int mi = 0; mi < 4; ++mi) {
#pragma unroll
        for (int ni = 0; ni < 4; ++ni) {
            const int col = bn + wn + ni * 16 + l15;
            const float bv = isb ? b2f(((const unsigned short*)bias)[col])
                                 : ((const float*)bias)[col];
#pragma unroll
            for (int r = 0; r < 4; ++r) {
                const int row = bm + wm + mi * 16 + l4 * 4 + r;
                float v = acc[mi][ni][r] + bv;
                const int which = col >> 10;
                const int h = (col >> 6) & 15;
                const int d = col & 63;
                const int b = row >> 11, t = row & 2047;
                const size_t idx = (((size_t)b * HH + h) * TT + t) * DD + d;
                if (which == 0)      outQ[idx] = f2b(v * 0.18033688f);  // /sqrt(64)*log2e
                else if (which == 1) outK[idx] = f2b(v);
                else                 outV[idx] = f2b(v);
            }
        }
    }
}

// ---------------- flash attention v5 (unchanged from round 11) ----------------
__global__ __launch_bounds__(256) void attn_k(unsigned short* __restrict__ Q,
                                              const unsigned short* __restrict__ K,
                                              const unsigned short* __restrict__ VT) {
    __shared__ __align__(16) char shmem[32000];
    const int tid = threadIdx.x, lane = tid & 63, h = tid >> 6;
    const int bid = blockIdx.x;
    const int swb = (bid & 7) * 256 + (bid >> 3);   // XCD swizzle (2048%8==0)
    const int bh = swb >> 5;
    const int pair = swb & 31;
    const int l15 = lane & 15, l4 = lane >> 4;
    unsigned short* Qp = Q + (size_t)bh * TT * DD;
    const unsigned short* Kp = K + (size_t)bh * TT * DD;
    const unsigned short* Vp = VT + (size_t)bh * DD * TT;
    const int swz = (l15 & 7) << 4;
    unsigned short (*PldsW)[64] = (unsigned short (*)[64])(shmem + h * 4096);
    unsigned char* prowA = (unsigned char*)&PldsW[l15][0];
    unsigned char* prowB = (unsigned char*)&PldsW[16 + l15][0];
    float* MrgF = (float*)shmem;
    unsigned short (*Olds)[34] = (unsigned short (*)[34])(shmem + 27648);

#pragma unroll 1
    for (int hv = 0; hv < 2; ++hv) {
        const int qt = hv ? (63 - pair) : pair;
        const int qw = qt << 5;
        const int qiA = qw + l15, qiB = qw + 16 + l15;
        const int kend = qw + 32;

        short8 qfA0 = *(const short8*)(Qp + (size_t)(qw + l15) * DD + l4 * 8);
        short8 qfA1 = *(const short8*)(Qp + (size_t)(qw + l15) * DD + 32 + l4 * 8);
        short8 qfB0 = *(const short8*)(Qp + (size_t)(qw + 16 + l15) * DD + l4 * 8);
        short8 qfB1 = *(const short8*)(Qp + (size_t)(qw + 16 + l15) * DD + 32 + l4 * 8);

        f32x4 otA[4], otB[4];
#pragma unroll
        for (int c = 0; c < 4; ++c) {
            otA[c] = (f32x4){0.f, 0.f, 0.f, 0.f};
            otB[c] = (f32x4){0.f, 0.f, 0.f, 0.f};
        }
        float mA = -1e30f, lA = 0.f, mB = -1e30f, lB = 0.f;

        auto softmax16 = [&](f32x4 (&st)[4], float& m, float& lsum, f32x4 (&ot)[4],
                             int qi, bool needMask, int kb, unsigned char* prow) {
            if (needMask) {
#pragma unroll
                for (int t = 0; t < 4; ++t)
#pragma unroll
                    for (int r = 0; r < 4; ++r) {
                        const int kpos = kb + t * 16 + l4 * 4 + r;
                        st[t][r] = (kpos > qi) ? -30000.f : st[t][r];
                    }
            }
            float mx0 = fmaxf(fmaxf(st[0][0], st[0][1]), fmaxf(st[0][2], st[0][3]));
            float mx1 = fmaxf(fmaxf(st[1][0], st[1][1]), fmaxf(st[1][2], st[1][3]));
            float mx2 = fmaxf(fmaxf(st[2][0], st[2][1]), fmaxf(st[2][2], st[2][3]));
            float mx3 = fmaxf(fmaxf(st[3][0], st[3][1]), fmaxf(st[3][2], st[3][3]));
            float tmax = fmaxf(fmaxf(mx0, mx1), fmaxf(mx2, mx3));
            tmax = fmaxf(tmax, __shfl_xor(tmax, 16));
            tmax = fmaxf(tmax, __shfl_xor(tmax, 32));
            if (!__all(tmax <= m + 8.f)) {       // T13 defer-max
                const float mnew = fmaxf(m, tmax);
                const float corr = exp2_hw(m - mnew);
                lsum *= corr;
#pragma unroll
                for (int c = 0; c < 4; ++c) ot[c] *= corr;
                m = mnew;
            }
            u16x4 pw[4];
            float s0 = 0.f, s1 = 0.f, s2 = 0.f, s3 = 0.f;
#pragma unroll
            for (int t = 0; t < 4; ++t)
#pragma unroll
                for (int r = 0; r < 4; ++r) {
                    float p = exp2_hw(st[t][r] - m);
                    if (t == 0) s0 += p; else if (t == 1) s1 += p;
                    else if (t == 2) s2 += p; else s3 += p;
                    pw[t][r] = f2b(p);
                }
            lsum += (s0 + s1) + (s2 + s3);
#pragma unroll
            for (int t = 0; t < 4; ++t)
                *(u16x4*)(prow + ((t * 32 + l4 * 8) ^ swz)) = pw[t];
        };

#pragma unroll 1
        for (int kb = h * 64; kb < kend; kb += 256) {
            short8 kf[4][2];
#pragma unroll
            for (int t = 0; t < 4; ++t) {
                const unsigned short* kr = Kp + (size_t)(kb + t * 16 + l15) * DD + l4 * 8;
                kf[t][0] = *(const short8*)(kr);
                kf[t][1] = *(const short8*)(kr + 32);
            }
            short8 vf[4][2];
#pragma unroll
            for (int c = 0; c < 4; ++c)
#pragma unroll
                for (int ch = 0; ch < 2; ++ch)
                    vf[c][ch] = *(const short8*)(Vp + (size_t)(c * 16 + l15) * TT
                                                 + kb + ch * 32 + l4 * 8);
            f32x4 st[4];
            __builtin_amdgcn_s_setprio(1);
#pragma unroll
            for (int t = 0; t < 4; ++t) {
                f32x4 z = (f32x4){0.f, 0.f, 0.f, 0.f};
                z = __builtin_amdgcn_mfma_f32_16x16x32_bf16(kf[t][0], qfA0, z, 0, 0, 0);
                z = __builtin_amdgcn_mfma_f32_16x16x32_bf16(kf[t][1], qfA1, z, 0, 0, 0);
                st[t] = z;
            }
            __builtin_amdgcn_s_setprio(0);
            softmax16(st, mA, lA, otA, qiA, kb + 63 > qw, kb, prowA);
            __builtin_amdgcn_s_setprio(1);
#pragma unroll
            for (int t = 0; t < 4; ++t) {
                f32x4 z = (f32x4){0.f, 0.f, 0.f, 0.f};
                z = __builtin_amdgcn_mfma_f32_16x16x32_bf16(kf[t][0], qfB0, z, 0, 0, 0);
                z = __builtin_amdgcn_mfma_f32_16x16x32_bf16(kf[t][1], qfB1, z, 0, 0, 0);
                st[t] = z;
            }
            __builtin_amdgcn_s_setprio(0);
            softmax16(st, mB, lB, otB, qiB, kb + 63 > qw + 16, kb, prowB);
            asm volatile("" ::: "memory");
            short8 pbA0 = *(const short8*)(prowA + ((l4 * 16) ^ swz));
            short8 pbA1 = *(const short8*)(prowA + ((64 + l4 * 16) ^ swz));
            short8 pbB0 = *(const short8*)(prowB + ((l4 * 16) ^ swz));
            short8 pbB1 = *(const short8*)(prowB + ((64 + l4 * 16) ^ swz));
            asm volatile("" ::: "memory");
            __builtin_amdgcn_s_setprio(1);
#pragma unroll
            for (int c = 0; c < 4; ++c) {
                otA[c] = __builtin_amdgcn_mfma_f32_16x16x32_bf16(vf[c][0], pbA0, otA[c], 0, 0, 0);
                otA[c] = __builtin_amdgcn_mfma_f32_16x16x32_bf16(vf[c][1], pbA1, otA[c], 0, 0, 0);
                otB[c] = __builtin_amdgcn_mfma_f32_16x16x32_bf16(vf[c][0], pbB0, otB[c], 0, 0, 0);
                otB[c] = __builtin_amdgcn_mfma_f32_16x16x32_bf16(vf[c][1], pbB1, otB[c], 0, 0, 0);
            }
            __builtin_amdgcn_s_setprio(0);
        }

        float lsA = lA + __shfl_xor(lA, 16);
        lsA += __shfl_xor(lsA, 32);
        float lsB = lB + __shfl_xor(lB, 16);
        lsB += __shfl_xor(lsB, 32);

        __syncthreads();
        if (h > 0) {
            float* mb = MrgF + ((size_t)(h - 1) * 64 + lane) * 36;
            mb[0] = mA; mb[1] = lsA; mb[2] = mB; mb[3] = lsB;
#pragma unroll
            for (int c = 0; c < 4; ++c)
#pragma unroll
                for (int r = 0; r < 4; ++r) {
                    mb[4 + c * 4 + r]  = otA[c][r];
                    mb[20 + c * 4 + r] = otB[c][r];
                }
        }
        __syncthreads();
        if (h == 0) {
            auto merge16 = [&](float m0, float ls0, const f32x4 (&ot)[4],
                               int mOff, int oOff, int col) {
                float mj[3], lj[3];
                float mstar = m0;
#pragma unroll
                for (int j = 0; j < 3; ++j) {
                    mj[j] = MrgF[((size_t)j * 64 + lane) * 36 + mOff];
                    lj[j] = MrgF[((size_t)j * 64 + lane) * 36 + mOff + 1];
                    mstar = fmaxf(mstar, mj[j]);
                }
                const float cs = exp2_hw(m0 - mstar);
                float cj[3];
                float den = ls0 * cs;
#pragma unroll
                for (int j = 0; j < 3; ++j) {
                    cj[j] = exp2_hw(mj[j] - mstar);
                    den += lj[j] * cj[j];
                }
                const float inv = 1.f / den;
#pragma unroll
                for (int c = 0; c < 4; ++c)
#pragma unroll
                    for (int r = 0; r < 4; ++r) {
                        float v = ot[c][r] * cs;
#pragma unroll
                        for (int j = 0; j < 3; ++j)
                            v += MrgF[((size_t)j * 64 + lane) * 36 + oOff + c * 4 + r] * cj[j];
                        v *= inv;
                        if (!finite_f(v)) v = 200.0f;   // canary
                        Olds[c * 16 + l4 * 4 + r][col] = f2b(v);
                    }
            };
            merge16(mA, lsA, otA, 0, 4, l15);
            merge16(mB, lsB, otB, 2, 20, 16 + l15);
            asm volatile("" ::: "memory");
            const int qr = lane >> 1, hf = lane & 1;
#pragma unroll
            for (int chunk = 0; chunk < 4; ++chunk) {
                u16x8 o;
#pragma unroll
                for (int j = 0; j < 8; ++j) o[j] = Olds[hf * 32 + chunk * 8 + j][qr];
                *(u16x8*)(Qp + (size_t)(qw + qr) * DD + hf * 32 + chunk * 8) = o;
            }
        }
        __syncthreads();
    }
}

// -------- proj GEMM: Y([b][h][t][d] in Q region) @ WprojT + bias -> out fp32 --------
__global__ __launch_bounds__(256) void gemm_proj(const unsigned short* __restrict__ A,
                                                 const unsigned short* __restrict__ Bt,
                                                 const void* __restrict__ bias,
                                                 float* __restrict__ outO,
                                                 const int* __restrict__ flag) {
    __shared__ unsigned short As[128 * 32];
    __shared__ unsigned short Bs[128 * 32];
    const int Ksz = CCH;
    const int tid = threadIdx.x;
    const int lane = tid & 63;
    const int wid = tid >> 6;
    const int bm = blockIdx.y * 128;
    const int bn = blockIdx.x * 128;
    const int wm = (wid >> 1) * 64;
    const int wn = (wid & 1) * 64;
    const int sr = tid >> 2;
    const int sc = (tid & 3) * 8;
    const int l15 = lane & 15, l4 = lane >> 4;
    const int isb = *flag;

    f32x4 acc[4][4];
#pragma unroll
    for (int i = 0; i < 4; ++i)
#pragma unroll
        for (int j = 0; j < 4; ++j)
            acc[i][j] = (f32x4){0.f, 0.f, 0.f, 0.f};

    // A logical row m=b*2048+t, col k=h*64+d; stored [b][h][t][d]
    const int m0 = bm + sr;
    const unsigned short* Ar0 = A + (size_t)(m0 >> 11) * (HH * TT * DD)
                                  + (size_t)(m0 & 2047) * DD;
    const unsigned short* Ar1 = Ar0 + (size_t)64 * DD;
    const unsigned short* pb0 = Bt + (size_t)(bn + sr) * Ksz + sc;
    const unsigned short* pb1 = pb0 + (size_t)64 * Ksz;
    unsigned short* lA0 = &As[sr * 32 + sc];
    unsigned short* lA1 = &As[(sr + 64) * 32 + sc];
    unsigned short* lB0 = &Bs[sr * 32 + sc];
    unsigned short* lB1 = &Bs[(sr + 64) * 32 + sc];

    auto aoff = [&](int kt) -> size_t {   // kt%64 in {0,32}; slab within one h
        return (size_t)(kt >> 6) * (TT * DD) + (kt & 32) + sc;
    };

    for (int kt = 0; kt < Ksz; kt += 32) {
        __syncthreads();
        gl_lds16(Ar0 + aoff(kt), lA0);
        gl_lds16(Ar1 + aoff(kt), lA1);
        gl_lds16(pb0 + kt, lB0);
        gl_lds16(pb1 + kt, lB1);
        __syncthreads();
        short8 af[4], bfr[4];
#pragma unroll
        for (int mi = 0; mi < 4; ++mi)
            af[mi] = *(const short8*)&As[(wm + mi * 16 + l15) * 32 + l4 * 8];
#pragma unroll
        for (int ni = 0; ni < 4; ++ni)
            bfr[ni] = *(const short8*)&Bs[(wn + ni * 16 + l15) * 32 + l4 * 8];
#pragma unroll
        for (int mi = 0; mi < 4; ++mi)
#pragma unroll
            for (int ni = 0; ni < 4; ++ni)
                acc[mi][ni] = __builtin_amdgcn_mfma_f32_16x16x32_bf16(
                    af[mi], bfr[ni], acc[mi][ni], 0, 0, 0);
    }

#pragma unroll
    for (int mi = 0; mi < 4; ++mi) {
#pragma unroll
        for (int ni = 0; ni < 4; ++ni) {
            const int col = bn + wn + ni * 16 + l15;
            const float bv = isb ? b2f(((const unsigned short*)bias)[col])
                                 : ((const float*)bias)[col];
#pragma unroll
            for (int r = 0; r < 4; ++r) {
                const int row = bm + wm + mi * 16 + l4 * 4 + r;
                float v = acc[mi][ni][r] + bv;
                if (!finite_f(v)) v = 300.0f;   // canary
                outO[(size_t)row * CCH + col] = v;
            }
        }
    }
}

extern "C" void kernel_launch(void* const* d_in, const int* in_sizes, int n_in,
                              void* d_out, int out_size, void* d_ws, size_t ws_size,
                              hipStream_t stream) {
    const void* x     = d_in[0];
    const void* Wqkv  = d_in[1];
    const void* bqkv  = d_in[2];
    const void* Wproj = d_in[3];
    const void* bproj = d_in[4];
    float* out = (float*)d_out;

    // workspace: 58.7 MB; d_out doubles as scratch: [xb 16.78MB | Vstage 16.78MB]
    char* w = (char*)d_ws;
    int* flag = (int*)w;                          w += 256;
    unsigned short* wqkvT  = (unsigned short*)w;  w += (size_t)3 * CCH * CCH * 2;
    unsigned short* wprojT = (unsigned short*)w;  w += (size_t)CCH * CCH * 2;
    unsigned short* Qb     = (unsigned short*)w;  w += (size_t)MM * CCH * 2;
    unsigned short* Kb     = (unsigned short*)w;  w += (size_t)MM * CCH * 2;
    unsigned short* VTb    = (unsigned short*)w;  w += (size_t)MM * CCH * 2;
    unsigned short* xb     = (unsigned short*)d_out;                     // first half
    unsigned short* Vstage = (unsigned short*)d_out + (size_t)MM * CCH;  // second half

    detect_k<<<1, 64, 0, stream>>>((const unsigned int*)x, flag);
    cast_x_k<<<MM * CCH / 8 / 256, 256, 0, stream>>>(x, xb, flag);
    wtrans_k<<<dim3(96, 32), 256, 0, stream>>>(Wqkv, wqkvT, CCH, 3 * CCH, flag);
    wtrans_k<<<dim3(32, 32), 256, 0, stream>>>(Wproj, wprojT, CCH, CCH, flag);
    gemm_qkv<<<dim3(24, 64), 256, 0, stream>>>(xb, wqkvT, bqkv, Qb, Kb, Vstage, flag);
    vtrans_k<<<dim3(32, 64), 256, 0, stream>>>(Vstage, VTb);
    attn_k<<<2048, 256, 0, stream>>>(Qb, Kb, VTb);          // writes Y over Q rows
    gemm_proj<<<dim3(8, 64), 256, 0, stream>>>(Qb, wprojT, bproj, out, flag);
}

// Round 13
// 273.270 us; speedup vs baseline: 2.0761x; 1.0203x over previous
//
#include <hip/hip_runtime.h>
#include <hip/hip_bf16.h>

#define TT 2048
#define CCH 1024
#define HH 16
#define DD 64
#define BB 4
#define MM (BB*TT)

typedef __attribute__((ext_vector_type(4))) float f32x4;
typedef __attribute__((ext_vector_type(8))) short short8;
typedef __attribute__((ext_vector_type(8))) unsigned short u16x8;
typedef __attribute__((ext_vector_type(4))) unsigned short u16x4;

__device__ __forceinline__ unsigned short f2b(float f) {
    unsigned int u = __float_as_uint(f);
    u += 0x7fffu + ((u >> 16) & 1u);
    return (unsigned short)(u >> 16);
}
// native HW convert (compiler emits v_cvt_pk_bf16_f32 for pairs)
__device__ __forceinline__ unsigned short f2b_hw(float f) {
    __hip_bfloat16 h = __float2bfloat16(f);
    return reinterpret_cast<unsigned short&>(h);
}
__device__ __forceinline__ float b2f(unsigned short u) {
    return __uint_as_float(((unsigned int)u) << 16);
}
__device__ __forceinline__ int finite_f(float v) {
    return ((__float_as_uint(v) >> 23) & 0xFFu) != 0xFFu;
}
__device__ __forceinline__ float exp2_hw(float x) {
    return __builtin_amdgcn_exp2f(x);
}

// async global->LDS, 16B per lane (dest must be wave-uniform base + lane*16)
typedef const __attribute__((address_space(1))) unsigned int g_u32;
typedef __attribute__((address_space(3))) unsigned int l_u32;
__device__ __forceinline__ void gl_lds16(const unsigned short* g, unsigned short* l) {
    __builtin_amdgcn_global_load_lds((g_u32*)g, (l_u32*)l, 16, 0, 0);
}

// ---------------- input-dtype detector ----------------
__global__ __launch_bounds__(64) void detect_k(const unsigned int* __restrict__ x,
                                               int* __restrict__ flag) {
    int tid = threadIdx.x;
    int cnt = 0;
#pragma unroll
    for (int i = 0; i < 16; ++i) {
        unsigned int w = x[tid * 16 + i];
        unsigned int lo = w & 0xFFFFu;
        unsigned int e = (lo >> 7) & 0xFFu;
        if ((e >= 0x62u && e <= 0x90u) || lo == 0u) ++cnt;
    }
#pragma unroll
    for (int o = 32; o; o >>= 1) cnt += __shfl_down(cnt, o);
    if (tid == 0) *flag = (cnt >= 640) ? 1 : 0;
}

// ---------------- cast/copy x -> bf16 ----------------
__global__ __launch_bounds__(256) void cast_x_k(const void* __restrict__ in,
                                                unsigned short* __restrict__ out,
                                                const int* __restrict__ flag) {
    int g = blockIdx.x * 256 + threadIdx.x;
    if (*flag) {
        *(u16x8*)(out + (size_t)g * 8) =
            *(const u16x8*)((const unsigned short*)in + (size_t)g * 8);
    } else {
        const float4* p = (const float4*)((const float*)in + (size_t)g * 8);
        float4 v0 = p[0], v1 = p[1];
        u16x8 o;
        o[0] = f2b(v0.x); o[1] = f2b(v0.y); o[2] = f2b(v0.z); o[3] = f2b(v0.w);
        o[4] = f2b(v1.x); o[5] = f2b(v1.y); o[6] = f2b(v1.z); o[7] = f2b(v1.w);
        *(u16x8*)(out + (size_t)g * 8) = o;
    }
}

// ------------- W transpose(+cast): [R][Cc] -> bf16 [Cc][R] -------------
__global__ __launch_bounds__(256) void wtrans_k(const void* __restrict__ in,
                                                unsigned short* __restrict__ out,
                                                int R, int Cc,
                                                const int* __restrict__ flag) {
    __shared__ float tile[32][33];
    const int tid = threadIdx.x;
    const int c0 = blockIdx.x * 32, r0 = blockIdx.y * 32;
    const int isb = *flag;
#pragma unroll
    for (int i = 0; i < 4; ++i) {
        int e = i * 256 + tid;
        int row = e >> 5, col = e & 31;
        size_t idx = (size_t)(r0 + row) * Cc + (c0 + col);
        tile[row][col] = isb ? b2f(((const unsigned short*)in)[idx])
                             : ((const float*)in)[idx];
    }
    __syncthreads();
#pragma unroll
    for (int i = 0; i < 4; ++i) {
        int e = i * 256 + tid;
        int crow = e >> 5, rcol = e & 31;
        out[(size_t)(c0 + crow) * R + (r0 + rcol)] = f2b(tile[rcol][crow]);
    }
}

// ------------- V transpose: bf16 [bh][2048][64] -> [bh][64][2048] -------------
__global__ __launch_bounds__(256) void vtrans_k(const unsigned short* __restrict__ V,
                                                unsigned short* __restrict__ VT) {
    __shared__ unsigned short tile[64][68];
    const int tid = threadIdx.x;
    const int t0 = blockIdx.x * 64;
    const int bh = blockIdx.y;
    const unsigned short* in = V + ((size_t)bh * TT + t0) * DD;
#pragma unroll
    for (int i = 0; i < 4; ++i) {
        int cid = i * 256 + tid;
        int row = cid >> 4;
        int ch  = cid & 15;
        u16x4 v = *(const u16x4*)(in + row * DD + ch * 4);
        *(u16x4*)&tile[row][ch * 4] = v;
    }
    __syncthreads();
    unsigned short* out = VT + (size_t)bh * DD * TT + t0;
#pragma unroll
    for (int i = 0; i < 4; ++i) {
        int cid = i * 256 + tid;
        int drow = cid >> 4;
        int tch  = cid & 15;
        u16x4 v;
        v[0] = tile[tch * 4 + 0][drow];
        v[1] = tile[tch * 4 + 1][drow];
        v[2] = tile[tch * 4 + 2][drow];
        v[3] = tile[tch * 4 + 3][drow];
        *(u16x4*)(out + (size_t)drow * TT + tch * 4) = v;
    }
}

// -------- QKV GEMM: xb[M][K] bf16 @ WqkvT[N][K] bf16 + bias --------
__global__ __launch_bounds__(256) void gemm_qkv(const unsigned short* __restrict__ A,
                                                const unsigned short* __restrict__ Bt,
                                                const void* __restrict__ bias,
                                                unsigned short* __restrict__ outQ,
                                                unsigned short* __restrict__ outK,
                                                unsigned short* __restrict__ outV,
                                                const int* __restrict__ flag) {
    __shared__ unsigned short As[128 * 32];
    __shared__ unsigned short Bs[128 * 32];
    const int Ksz = CCH;
    const int tid = threadIdx.x;
    const int lane = tid & 63;
    const int wid = tid >> 6;
    const int bm = blockIdx.y * 128;
    const int bn = blockIdx.x * 128;
    const int wm = (wid >> 1) * 64;
    const int wn = (wid & 1) * 64;
    const int sr = tid >> 2;
    const int sc = (tid & 3) * 8;
    const int l15 = lane & 15, l4 = lane >> 4;
    const int isb = *flag;

    f32x4 acc[4][4];
#pragma unroll
    for (int i = 0; i < 4; ++i)
#pragma unroll
        for (int j = 0; j < 4; ++j)
            acc[i][j] = (f32x4){0.f, 0.f, 0.f, 0.f};

    const unsigned short* pa0 = A + (size_t)(bm + sr) * Ksz + sc;
    const unsigned short* pa1 = pa0 + (size_t)64 * Ksz;
    const unsigned short* pb0 = Bt + (size_t)(bn + sr) * Ksz + sc;
    const unsigned short* pb1 = pb0 + (size_t)64 * Ksz;
    unsigned short* lA0 = &As[sr * 32 + sc];
    unsigned short* lA1 = &As[(sr + 64) * 32 + sc];
    unsigned short* lB0 = &Bs[sr * 32 + sc];
    unsigned short* lB1 = &Bs[(sr + 64) * 32 + sc];

    for (int kt = 0; kt < Ksz; kt += 32) {
        __syncthreads();
        gl_lds16(pa0 + kt, lA0);
        gl_lds16(pa1 + kt, lA1);
        gl_lds16(pb0 + kt, lB0);
        gl_lds16(pb1 + kt, lB1);
        __syncthreads();
        short8 af[4], bfr[4];
#pragma unroll
        for (int mi = 0; mi < 4; ++mi)
            af[mi] = *(const short8*)&As[(wm + mi * 16 + l15) * 32 + l4 * 8];
#pragma unroll
        for (int ni = 0; ni < 4; ++ni)
            bfr[ni] = *(const short8*)&Bs[(wn + ni * 16 + l15) * 32 + l4 * 8];
#pragma unroll
        for (int mi = 0; mi < 4; ++mi)
#pragma unroll
            for (int ni = 0; ni < 4; ++ni)
                acc[mi][ni] = __builtin_amdgcn_mfma_f32_16x16x32_bf16(
                    af[mi], bfr[ni], acc[mi][ni], 0, 0, 0);
    }

#pragma unroll
    for (int mi = 0; mi < 4; ++mi) {
#pragma unroll
        for (int ni = 0; ni < 4; ++ni) {
            const int col = bn + wn + ni * 16 + l15;
            const float bv = isb ? b2f(((const unsigned short*)bias)[col])
                                 : ((const float*)bias)[col];
#pragma unroll
            for (int r = 0; r < 4; ++r) {
                const int row = bm + wm + mi * 16 + l4 * 4 + r;
                float v = acc[mi][ni][r] + bv;
                const int which = col >> 10;
                const int h = (col >> 6) & 15;
                const int d = col & 63;
                const int b = row >> 11, t = row & 2047;
                const size_t idx = (((size_t)b * HH + h) * TT + t) * DD + d;
                if (which == 0)      outQ[idx] = f2b(v * 0.18033688f);  // /sqrt(64)*log2e
                else if (which == 1) outK[idx] = f2b(v);
                else                 outV[idx] = f2b(v);
            }
        }
    }
}

// ---------------- flash attention v6: v5 + K-prefetch + native cvt ----------------
// Per iteration: QK_A -> sm_A -> QK_B -> [prefetch K(i+1) into same regs + V]
// -> sm_B -> P reads -> PV. K(i+1) latency hides under sm_B+LDS+PV; zero extra
// VGPR (kf recycled). Softmax pack uses native bf16 cvt (v_cvt_pk fusion).
__global__ __launch_bounds__(256) void attn_k(unsigned short* __restrict__ Q,
                                              const unsigned short* __restrict__ K,
                                              const unsigned short* __restrict__ VT) {
    __shared__ __align__(16) char shmem[32000];
    const int tid = threadIdx.x, lane = tid & 63, h = tid >> 6;
    const int bid = blockIdx.x;
    const int swb = (bid & 7) * 256 + (bid >> 3);   // XCD swizzle (2048%8==0)
    const int bh = swb >> 5;
    const int pair = swb & 31;
    const int l15 = lane & 15, l4 = lane >> 4;
    unsigned short* Qp = Q + (size_t)bh * TT * DD;
    const unsigned short* Kp = K + (size_t)bh * TT * DD;
    const unsigned short* Vp = VT + (size_t)bh * DD * TT;
    const int swz = (l15 & 7) << 4;
    unsigned short (*PldsW)[64] = (unsigned short (*)[64])(shmem + h * 4096);
    unsigned char* prowA = (unsigned char*)&PldsW[l15][0];
    unsigned char* prowB = (unsigned char*)&PldsW[16 + l15][0];
    float* MrgF = (float*)shmem;
    unsigned short (*Olds)[34] = (unsigned short (*)[34])(shmem + 27648);

#pragma unroll 1
    for (int hv = 0; hv < 2; ++hv) {
        const int qt = hv ? (63 - pair) : pair;
        const int qw = qt << 5;
        const int qiA = qw + l15, qiB = qw + 16 + l15;
        const int kend = qw + 32;

        short8 qfA0 = *(const short8*)(Qp + (size_t)(qw + l15) * DD + l4 * 8);
        short8 qfA1 = *(const short8*)(Qp + (size_t)(qw + l15) * DD + 32 + l4 * 8);
        short8 qfB0 = *(const short8*)(Qp + (size_t)(qw + 16 + l15) * DD + l4 * 8);
        short8 qfB1 = *(const short8*)(Qp + (size_t)(qw + 16 + l15) * DD + 32 + l4 * 8);

        f32x4 otA[4], otB[4];
#pragma unroll
        for (int c = 0; c < 4; ++c) {
            otA[c] = (f32x4){0.f, 0.f, 0.f, 0.f};
            otB[c] = (f32x4){0.f, 0.f, 0.f, 0.f};
        }
        float mA = -1e30f, lA = 0.f, mB = -1e30f, lB = 0.f;

        // softmax over one 16-row subtile; packs P into LDS (swizzled)
        auto softmax16 = [&](f32x4 (&st)[4], float& m, float& lsum, f32x4 (&ot)[4],
                             int qi, bool needMask, int kb, unsigned char* prow) {
            if (needMask) {
#pragma unroll
                for (int t = 0; t < 4; ++t)
#pragma unroll
                    for (int r = 0; r < 4; ++r) {
                        const int kpos = kb + t * 16 + l4 * 4 + r;
                        st[t][r] = (kpos > qi) ? -30000.f : st[t][r];
                    }
            }
            float mx0 = fmaxf(fmaxf(st[0][0], st[0][1]), fmaxf(st[0][2], st[0][3]));
            float mx1 = fmaxf(fmaxf(st[1][0], st[1][1]), fmaxf(st[1][2], st[1][3]));
            float mx2 = fmaxf(fmaxf(st[2][0], st[2][1]), fmaxf(st[2][2], st[2][3]));
            float mx3 = fmaxf(fmaxf(st[3][0], st[3][1]), fmaxf(st[3][2], st[3][3]));
            float tmax = fmaxf(fmaxf(mx0, mx1), fmaxf(mx2, mx3));
            tmax = fmaxf(tmax, __shfl_xor(tmax, 16));
            tmax = fmaxf(tmax, __shfl_xor(tmax, 32));
            if (!__all(tmax <= m + 8.f)) {       // T13 defer-max
                const float mnew = fmaxf(m, tmax);
                const float corr = exp2_hw(m - mnew);
                lsum *= corr;
#pragma unroll
                for (int c = 0; c < 4; ++c) ot[c] *= corr;
                m = mnew;
            }
            u16x4 pw[4];
            float s0 = 0.f, s1 = 0.f, s2 = 0.f, s3 = 0.f;
#pragma unroll
            for (int t = 0; t < 4; ++t)
#pragma unroll
                for (int r = 0; r < 4; ++r) {
                    float p = exp2_hw(st[t][r] - m);
                    if (t == 0) s0 += p; else if (t == 1) s1 += p;
                    else if (t == 2) s2 += p; else s3 += p;
                    pw[t][r] = f2b_hw(p);        // native cvt (pairs fuse)
                }
            lsum += (s0 + s1) + (s2 + s3);
#pragma unroll
            for (int t = 0; t < 4; ++t)
                *(u16x4*)(prow + ((t * 32 + l4 * 8) ^ swz)) = pw[t];
        };

        // prologue: load first K tile
        short8 kf[4][2];
        {
            const int kb0 = h * 64;
            if (kb0 < kend) {
#pragma unroll
                for (int t = 0; t < 4; ++t) {
                    const unsigned short* kr = Kp + (size_t)(kb0 + t * 16 + l15) * DD + l4 * 8;
                    kf[t][0] = *(const short8*)(kr);
                    kf[t][1] = *(const short8*)(kr + 32);
                }
            }
        }

#pragma unroll 1
        for (int kb = h * 64; kb < kend; kb += 256) {
            // QK^T subtile A (uses prefetched kf)
            f32x4 st[4];
            __builtin_amdgcn_s_setprio(1);
#pragma unroll
            for (int t = 0; t < 4; ++t) {
                f32x4 z = (f32x4){0.f, 0.f, 0.f, 0.f};
                z = __builtin_amdgcn_mfma_f32_16x16x32_bf16(kf[t][0], qfA0, z, 0, 0, 0);
                z = __builtin_amdgcn_mfma_f32_16x16x32_bf16(kf[t][1], qfA1, z, 0, 0, 0);
                st[t] = z;
            }
            __builtin_amdgcn_s_setprio(0);
            softmax16(st, mA, lA, otA, qiA, kb + 63 > qw, kb, prowA);
            // QK^T subtile B (last consumer of kf)
            __builtin_amdgcn_s_setprio(1);
#pragma unroll
            for (int t = 0; t < 4; ++t) {
                f32x4 z = (f32x4){0.f, 0.f, 0.f, 0.f};
                z = __builtin_amdgcn_mfma_f32_16x16x32_bf16(kf[t][0], qfB0, z, 0, 0, 0);
                z = __builtin_amdgcn_mfma_f32_16x16x32_bf16(kf[t][1], qfB1, z, 0, 0, 0);
                st[t] = z;
            }
            __builtin_amdgcn_s_setprio(0);
            // V for this iteration (consumed after sm_B -> latency covered)
            short8 vf[4][2];
#pragma unroll
            for (int c = 0; c < 4; ++c)
#pragma unroll
                for (int ch = 0; ch < 2; ++ch)
                    vf[c][ch] = *(const short8*)(Vp + (size_t)(c * 16 + l15) * TT
                                                 + kb + ch * 32 + l4 * 8);
            // prefetch next iteration's K into the SAME regs (kf dead now);
            // latency hides under sm_B + P round-trip + PV
            const int kbn = kb + 256;
            if (kbn < kend) {
#pragma unroll
                for (int t = 0; t < 4; ++t) {
                    const unsigned short* kr = Kp + (size_t)(kbn + t * 16 + l15) * DD + l4 * 8;
                    kf[t][0] = *(const short8*)(kr);
                    kf[t][1] = *(const short8*)(kr + 32);
                }
            }
            softmax16(st, mB, lB, otB, qiB, kb + 63 > qw + 16, kb, prowB);
            asm volatile("" ::: "memory");
            short8 pbA0 = *(const short8*)(prowA + ((l4 * 16) ^ swz));
            short8 pbA1 = *(const short8*)(prowA + ((64 + l4 * 16) ^ swz));
            short8 pbB0 = *(const short8*)(prowB + ((l4 * 16) ^ swz));
            short8 pbB1 = *(const short8*)(prowB + ((64 + l4 * 16) ^ swz));
            asm volatile("" ::: "memory");
            __builtin_amdgcn_s_setprio(1);
#pragma unroll
            for (int c = 0; c < 4; ++c) {
                otA[c] = __builtin_amdgcn_mfma_f32_16x16x32_bf16(vf[c][0], pbA0, otA[c], 0, 0, 0);
                otA[c] = __builtin_amdgcn_mfma_f32_16x16x32_bf16(vf[c][1], pbA1, otA[c], 0, 0, 0);
                otB[c] = __builtin_amdgcn_mfma_f32_16x16x32_bf16(vf[c][0], pbB0, otB[c], 0, 0, 0);
                otB[c] = __builtin_amdgcn_mfma_f32_16x16x32_bf16(vf[c][1], pbB1, otB[c], 0, 0, 0);
            }
            __builtin_amdgcn_s_setprio(0);
        }

        float lsA = lA + __shfl_xor(lA, 16);
        lsA += __shfl_xor(lsA, 32);
        float lsB = lB + __shfl_xor(lB, 16);
        lsB += __shfl_xor(lsB, 32);

        __syncthreads();
        if (h > 0) {
            float* mb = MrgF + ((size_t)(h - 1) * 64 + lane) * 36;
            mb[0] = mA; mb[1] = lsA; mb[2] = mB; mb[3] = lsB;
#pragma unroll
            for (int c = 0; c < 4; ++c)
#pragma unroll
                for (int r = 0; r < 4; ++r) {
                    mb[4 + c * 4 + r]  = otA[c][r];
                    mb[20 + c * 4 + r] = otB[c][r];
                }
        }
        __syncthreads();
        if (h == 0) {
            auto merge16 = [&](float m0, float ls0, const f32x4 (&ot)[4],
                               int mOff, int oOff, int col) {
                float mj[3], lj[3];
                float mstar = m0;
#pragma unroll
                for (int j = 0; j < 3; ++j) {
                    mj[j] = MrgF[((size_t)j * 64 + lane) * 36 + mOff];
                    lj[j] = MrgF[((size_t)j * 64 + lane) * 36 + mOff + 1];
                    mstar = fmaxf(mstar, mj[j]);
                }
                const float cs = exp2_hw(m0 - mstar);
                float cj[3];
                float den = ls0 * cs;
#pragma unroll
                for (int j = 0; j < 3; ++j) {
                    cj[j] = exp2_hw(mj[j] - mstar);
                    den += lj[j] * cj[j];
                }
                const float inv = 1.f / den;
#pragma unroll
                for (int c = 0; c < 4; ++c)
#pragma unroll
                    for (int r = 0; r < 4; ++r) {
                        float v = ot[c][r] * cs;
#pragma unroll
                        for (int j = 0; j < 3; ++j)
                            v += MrgF[((size_t)j * 64 + lane) * 36 + oOff + c * 4 + r] * cj[j];
                        v *= inv;
                        if (!finite_f(v)) v = 200.0f;   // canary
                        Olds[c * 16 + l4 * 4 + r][col] = f2b(v);
                    }
            };
            merge16(mA, lsA, otA, 0, 4, l15);
            merge16(mB, lsB, otB, 2, 20, 16 + l15);
            asm volatile("" ::: "memory");
            const int qr = lane >> 1, hf = lane & 1;
#pragma unroll
            for (int chunk = 0; chunk < 4; ++chunk) {
                u16x8 o;
#pragma unroll
                for (int j = 0; j < 8; ++j) o[j] = Olds[hf * 32 + chunk * 8 + j][qr];
                *(u16x8*)(Qp + (size_t)(qw + qr) * DD + hf * 32 + chunk * 8) = o;
            }
        }
        __syncthreads();
    }
}

// -------- proj GEMM: Y([b][h][t][d] in Q region) @ WprojT + bias -> out fp32 --------
__global__ __launch_bounds__(256) void gemm_proj(const unsigned short* __restrict__ A,
                                                 const unsigned short* __restrict__ Bt,
                                                 const void* __restrict__ bias,
                                                 float* __restrict__ outO,
                                                 const int* __restrict__ flag) {
    __shared__ unsigned short As[128 * 32];
    __shared__ unsigned short Bs[128 * 32];
    const int Ksz = CCH;
    const int tid = threadIdx.x;
    const int lane = tid & 63;
    const int wid = tid >> 6;
    const int bm = blockIdx.y * 128;
    const int bn = blockIdx.x * 128;
    const int wm = (wid >> 1) * 64;
    const int wn = (wid & 1) * 64;
    const int sr = tid >> 2;
    const int sc = (tid & 3) * 8;
    const int l15 = lane & 15, l4 = lane >> 4;
    const int isb = *flag;

    f32x4 acc[4][4];
#pragma unroll
    for (int i = 0; i < 4; ++i)
#pragma unroll
        for (int j = 0; j < 4; ++j)
            acc[i][j] = (f32x4){0.f, 0.f, 0.f, 0.f};

    const int m0 = bm + sr;
    const unsigned short* Ar0 = A + (size_t)(m0 >> 11) * (HH * TT * DD)
                                  + (size_t)(m0 & 2047) * DD;
    const unsigned short* Ar1 = Ar0 + (size_t)64 * DD;
    const unsigned short* pb0 = Bt + (size_t)(bn + sr) * Ksz + sc;
    const unsigned short* pb1 = pb0 + (size_t)64 * Ksz;
    unsigned short* lA0 = &As[sr * 32 + sc];
    unsigned short* lA1 = &As[(sr + 64) * 32 + sc];
    unsigned short* lB0 = &Bs[sr * 32 + sc];
    unsigned short* lB1 = &Bs[(sr + 64) * 32 + sc];

    auto aoff = [&](int kt) -> size_t {
        return (size_t)(kt >> 6) * (TT * DD) + (kt & 32) + sc;
    };

    for (int kt = 0; kt < Ksz; kt += 32) {
        __syncthreads();
        gl_lds16(Ar0 + aoff(kt), lA0);
        gl_lds16(Ar1 + aoff(kt), lA1);
        gl_lds16(pb0 + kt, lB0);
        gl_lds16(pb1 + kt, lB1);
        __syncthreads();
        short8 af[4], bfr[4];
#pragma unroll
        for (int mi = 0; mi < 4; ++mi)
            af[mi] = *(const short8*)&As[(wm + mi * 16 + l15) * 32 + l4 * 8];
#pragma unroll
        for (int ni = 0; ni < 4; ++ni)
            bfr[ni] = *(const short8*)&Bs[(wn + ni * 16 + l15) * 32 + l4 * 8];
#pragma unroll
        for (int mi = 0; mi < 4; ++mi)
#pragma unroll
            for (int ni = 0; ni < 4; ++ni)
                acc[mi][ni] = __builtin_amdgcn_mfma_f32_16x16x32_bf16(
                    af[mi], bfr[ni], acc[mi][ni], 0, 0, 0);
    }

#pragma unroll
    for (int mi = 0; mi < 4; ++mi) {
#pragma unroll
        for (int ni = 0; ni < 4; ++ni) {
            const int col = bn + wn + ni * 16 + l15;
            const float bv = isb ? b2f(((const unsigned short*)bias)[col])
                                 : ((const float*)bias)[col];
#pragma unroll
            for (int r = 0; r < 4; ++r) {
                const int row = bm + wm + mi * 16 + l4 * 4 + r;
                float v = acc[mi][ni][r] + bv;
                if (!finite_f(v)) v = 300.0f;   // canary
                outO[(size_t)row * CCH + col] = v;
            }
        }
    }
}

extern "C" void kernel_launch(void* const* d_in, const int* in_sizes, int n_in,
                              void* d_out, int out_size, void* d_ws, size_t ws_size,
                              hipStream_t stream) {
    const void* x     = d_in[0];
    const void* Wqkv  = d_in[1];
    const void* bqkv  = d_in[2];
    const void* Wproj = d_in[3];
    const void* bproj = d_in[4];
    float* out = (float*)d_out;

    // workspace: 58.7 MB; d_out doubles as scratch: [xb 16.78MB | Vstage 16.78MB]
    char* w = (char*)d_ws;
    int* flag = (int*)w;                          w += 256;
    unsigned short* wqkvT  = (unsigned short*)w;  w += (size_t)3 * CCH * CCH * 2;
    unsigned short* wprojT = (unsigned short*)w;  w += (size_t)CCH * CCH * 2;
    unsigned short* Qb     = (unsigned short*)w;  w += (size_t)MM * CCH * 2;
    unsigned short* Kb     = (unsigned short*)w;  w += (size_t)MM * CCH * 2;
    unsigned short* VTb    = (unsigned short*)w;  w += (size_t)MM * CCH * 2;
    unsigned short* xb     = (unsigned short*)d_out;
    unsigned short* Vstage = (unsigned short*)d_out + (size_t)MM * CCH;

    detect_k<<<1, 64, 0, stream>>>((const unsigned int*)x, flag);
    cast_x_k<<<MM * CCH / 8 / 256, 256, 0, stream>>>(x, xb, flag);
    wtrans_k<<<dim3(96, 32), 256, 0, stream>>>(Wqkv, wqkvT, CCH, 3 * CCH, flag);
    wtrans_k<<<dim3(32, 32), 256, 0, stream>>>(Wproj, wprojT, CCH, CCH, flag);
    gemm_qkv<<<dim3(24, 64), 256, 0, stream>>>(xb, wqkvT, bqkv, Qb, Kb, Vstage, flag);
    vtrans_k<<<dim3(32, 64), 256, 0, stream>>>(Vstage, VTb);
    attn_k<<<2048, 256, 0, stream>>>(Qb, Kb, VTb);          // writes Y over Q rows
    gemm_proj<<<dim3(8, 64), 256, 0, stream>>>(Qb, wprojT, bproj, out, flag);
}